// Round 14
// baseline (2406.493 us; speedup 1.0000x reference)
//
#include <hip/hip_runtime.h>
#include <hip/hip_bf16.h>
#include <cstdint>
#include <cstddef>
#include <type_traits>

#define B_ALL 256
#define T_LEN 512
#define D_INP 64
#define HD    128
#define G4    512            // 4*H
#define NC    12
#define BCH   128            // batch per chunk
#define ROWS  (BCH * T_LEN)  // 65536 rows per chunk

// ---------- helpers ----------
__device__ __forceinline__ float bf2f(unsigned short u) {
    union { unsigned int i; float f; } v; v.i = ((unsigned int)u) << 16; return v.f;
}
__device__ __forceinline__ unsigned short f2bf(float f) {
    union { float f; unsigned int i; } v; v.f = f;
    unsigned int r = v.i + 0x7FFFu + ((v.i >> 16) & 1u);  // round-nearest-even
    return (unsigned short)(r >> 16);
}
__device__ __forceinline__ float sigf(float x) { return 1.0f / (1.0f + __expf(-x)); }
__device__ __forceinline__ float tanh_f(float x) {
    float xx = fminf(15.0f, fmaxf(-15.0f, x));
    float e = __expf(2.0f * xx);
    return (e - 1.0f) / (e + 1.0f);
}

// LDS-only barrier: drains lgkmcnt but leaves global loads/stores in flight.
#define LDS_BARRIER() asm volatile("s_waitcnt lgkmcnt(0)\n\ts_barrier" ::: "memory")

using bf16x8 = __attribute__((ext_vector_type(8))) short;
using f32x4  = __attribute__((ext_vector_type(4))) float;

// XOR swizzle for [R][32] bf16 LDS tiles (64B rows).
// R14: (r&7)<<4 (was (r&3)<<4). Frag reads touch 16 consecutive rows at 64B
// stride; XOR of byte bits 4-6 with r&7 maps rows 0..7 to bank-groups
// {0,20,8,28,16,4,24,12} (all distinct) -> 16 lanes land 2-way (free, m136)
// instead of 4-way (1.58x). Bit 6 crosses the 64B row boundary but the
// mapping is bijective and writes/reads share this function, so it is a pure
// layout change.
__device__ __forceinline__ int swz(int r, int kb) {
    return (r * 64 + kb) ^ ((r & 7) << 4);
}

// ---------- W split: fp32 -> hi/lo bf16 pair (hi+lo ~ fp32 exact) ----------
__global__ __launch_bounds__(256)
void split_w(const float* __restrict__ w, unsigned short* __restrict__ hi,
             unsigned short* __restrict__ lo, int n)
{
    int i = blockIdx.x * 256 + threadIdx.x;
    if (i < n) {
        float f = w[i];
        unsigned short h = f2bf(f);
        hi[i] = h;
        lo[i] = f2bf(f - bf2f(h));
    }
}

// ---------- gates GEMM (MFMA, split-precision bf16) ----------
template <int TERMS, typename TA>
__global__ __launch_bounds__(256)
void gates_gemm_mfma(const TA* __restrict__ A,
                     const unsigned short* __restrict__ Whi_g,
                     const unsigned short* __restrict__ Wlo_g,
                     const float* __restrict__ bias,
                     const int* __restrict__ lens,
                     unsigned short* __restrict__ out, int K)
{
    int row0 = blockIdx.x * 128;
    int col0 = blockIdx.y * 128;
    int bl = row0 >> 9;
    int t0 = row0 & (T_LEN - 1);
    if (t0 >= lens[bl]) return;

    __shared__ __align__(16) char smem[TERMS == 3 ? 32768 : 24576];
    char* sAhi = smem;                 // [128][32] bf16, swizzled
    char* sWhi = smem + 8192;
    char* sWlo = smem + 16384;
    char* sAlo = (TERMS == 3) ? smem + 24576 : smem;

    int tid = threadIdx.x;
    int l   = tid & 63;
    int w   = tid >> 6;
    int wr  = (w >> 1) * 64;
    int wc  = (w & 1) * 64;

    f32x4 acc[4][4];
#pragma unroll
    for (int mi = 0; mi < 4; ++mi)
#pragma unroll
        for (int ni = 0; ni < 4; ++ni) acc[mi][ni] = (f32x4){0.f, 0.f, 0.f, 0.f};

    int fr = l & 15;
    int fk = (l >> 4) * 16;

    for (int kt = 0; kt < K; kt += 32) {
#pragma unroll
        for (int q = 0; q < 2; ++q) {
            int c = tid + 256 * q;
            int r = c >> 2, kc = c & 3;
            size_t gi = (size_t)(col0 + r) * K + kt + kc * 8;
            *(uint4*)(sWhi + swz(r, kc * 16)) = *(const uint4*)&Whi_g[gi];
            *(uint4*)(sWlo + swz(r, kc * 16)) = *(const uint4*)&Wlo_g[gi];
        }
        if constexpr (std::is_same<TA, unsigned short>::value) {
#pragma unroll
            for (int q = 0; q < 2; ++q) {
                int c = tid + 256 * q;
                int r = c >> 2, kc = c & 3;
                *(uint4*)(sAhi + swz(r, kc * 16)) =
                    *(const uint4*)&A[(size_t)(row0 + r) * K + kt + kc * 8];
            }
        } else {
#pragma unroll
            for (int q = 0; q < 4; ++q) {
                int c = tid + 256 * q;
                int r = c >> 3, kc = c & 7;
                float4 f = *(const float4*)&A[(size_t)(row0 + r) * K + kt + kc * 4];
                ushort4 h, lo;
                h.x = f2bf(f.x); lo.x = f2bf(f.x - bf2f(h.x));
                h.y = f2bf(f.y); lo.y = f2bf(f.y - bf2f(h.y));
                h.z = f2bf(f.z); lo.z = f2bf(f.z - bf2f(h.z));
                h.w = f2bf(f.w); lo.w = f2bf(f.w - bf2f(h.w));
                *(ushort4*)(sAhi + swz(r, kc * 8)) = h;
                *(ushort4*)(sAlo + swz(r, kc * 8)) = lo;
            }
        }
        __syncthreads();

        bf16x8 ah[4], al[4], bh[4], bl4[4];
#pragma unroll
        for (int mi = 0; mi < 4; ++mi) {
            int off = swz(wr + mi * 16 + fr, fk);
            ah[mi] = *(const bf16x8*)(sAhi + off);
            if (TERMS == 3) al[mi] = *(const bf16x8*)(sAlo + off);
        }
#pragma unroll
        for (int ni = 0; ni < 4; ++ni) {
            int off = swz(wc + ni * 16 + fr, fk);
            bh[ni]  = *(const bf16x8*)(sWhi + off);
            bl4[ni] = *(const bf16x8*)(sWlo + off);
        }
#pragma unroll
        for (int mi = 0; mi < 4; ++mi)
#pragma unroll
            for (int ni = 0; ni < 4; ++ni) {
                acc[mi][ni] = __builtin_amdgcn_mfma_f32_16x16x32_bf16(
                    ah[mi], bh[ni], acc[mi][ni], 0, 0, 0);
                acc[mi][ni] = __builtin_amdgcn_mfma_f32_16x16x32_bf16(
                    ah[mi], bl4[ni], acc[mi][ni], 0, 0, 0);
                if (TERMS == 3)
                    acc[mi][ni] = __builtin_amdgcn_mfma_f32_16x16x32_bf16(
                        al[mi], bh[ni], acc[mi][ni], 0, 0, 0);
            }
        __syncthreads();
    }

    int r4 = (l >> 4) * 4;
#pragma unroll
    for (int ni = 0; ni < 4; ++ni) {
        int col = col0 + wc + ni * 16 + fr;
        float bj = bias[col];
#pragma unroll
        for (int mi = 0; mi < 4; ++mi) {
            int row = row0 + wr + mi * 16 + r4;
            f32x4 v = acc[mi][ni];
#pragma unroll
            for (int r = 0; r < 4; ++r)
                out[(size_t)(row + r) * 1024 + col] = f2bf(v[r] + bj);
        }
    }
}

// ---------- LSTM recurrence: proven R3/R5 structure (unchanged) ----------
__global__ __launch_bounds__(512)
void lstm_rec(const unsigned short* __restrict__ xg,   // [ROWS][1024]
              const float* __restrict__ Whh,           // [2][512][128]
              const int* __restrict__ lens,            // chunk-offset
              unsigned short* __restrict__ hs,         // [ROWS][256] or null
              float* __restrict__ hTf, float* __restrict__ hTb,
              int bOff)
{
    int dir = blockIdx.x >> 7;   // 128 batch per chunk
    int bl  = blockIdx.x & 127;
    int L   = lens[bl];
    int tid = threadIdx.x;
    int ks  = tid >> 7;          // k-quarter 0..3 (wave-uniform)
    int rr  = tid & 127;         // output index 0..127

    __shared__ float h_s[HD];
    __shared__ float gp[4][G4];

    float w[4][32];
#pragma unroll
    for (int g = 0; g < 4; ++g) {
        const float* wrow = Whh + ((size_t)dir * G4 + g * HD + rr) * HD + ks * 32;
#pragma unroll
        for (int k = 0; k < 32; k += 4) {
            float4 v = *(const float4*)(wrow + k);
            w[g][k] = v.x; w[g][k + 1] = v.y; w[g][k + 2] = v.z; w[g][k + 3] = v.w;
        }
    }

    if (tid < HD) h_s[tid] = 0.0f;
    float c = 0.0f, hkeep = 0.0f;
    __syncthreads();

    const unsigned short* xgb = xg + (size_t)bl * T_LEN * 1024 + (size_t)dir * G4;
    int tt   = dir ? (L - 1) : 0;
    int step = dir ? -1 : 1;

    float xv0 = 0.f, xv1 = 0.f, xv2 = 0.f, xv3 = 0.f;
    if (tid < HD) {
        const unsigned short* p = xgb + (size_t)tt * 1024;
        xv0 = bf2f(p[tid]);       xv1 = bf2f(p[tid + 128]);
        xv2 = bf2f(p[tid + 256]); xv3 = bf2f(p[tid + 384]);
    }

    for (int t = 0; t < L; ++t) {
        float a0 = 0.f, a1 = 0.f, a2 = 0.f, a3 = 0.f;
        const float* hq = &h_s[ks * 32];
#pragma unroll
        for (int k = 0; k < 32; k += 4) {
            float4 h4 = *(const float4*)(hq + k);
            a0 += w[0][k] * h4.x + w[0][k+1] * h4.y + w[0][k+2] * h4.z + w[0][k+3] * h4.w;
            a1 += w[1][k] * h4.x + w[1][k+1] * h4.y + w[1][k+2] * h4.z + w[1][k+3] * h4.w;
            a2 += w[2][k] * h4.x + w[2][k+1] * h4.y + w[2][k+2] * h4.z + w[2][k+3] * h4.w;
            a3 += w[3][k] * h4.x + w[3][k+1] * h4.y + w[3][k+2] * h4.z + w[3][k+3] * h4.w;
        }
        gp[ks][rr]       = a0;
        gp[ks][rr + 128] = a1;
        gp[ks][rr + 256] = a2;
        gp[ks][rr + 384] = a3;
        LDS_BARRIER();

        if (tid < HD) {
            float gi = xv0 + ((gp[0][tid]       + gp[1][tid])       + (gp[2][tid]       + gp[3][tid]));
            float gf = xv1 + ((gp[0][tid + 128] + gp[1][tid + 128]) + (gp[2][tid + 128] + gp[3][tid + 128]));
            float gg = xv2 + ((gp[0][tid + 256] + gp[1][tid + 256]) + (gp[2][tid + 256] + gp[3][tid + 256]));
            float go = xv3 + ((gp[0][tid + 384] + gp[1][tid + 384]) + (gp[2][tid + 384] + gp[3][tid + 384]));

            int ttn = (t + 1 < L) ? (tt + step) : tt;
            const unsigned short* p = xgb + (size_t)ttn * 1024;
            xv0 = bf2f(p[tid]);       xv1 = bf2f(p[tid + 128]);
            xv2 = bf2f(p[tid + 256]); xv3 = bf2f(p[tid + 384]);

            float ig = sigf(gi);
            float fg = sigf(gf);
            float G  = tanh_f(gg);
            float og = sigf(go);
            c = fg * c + ig * G;
            float hn = og * tanh_f(c);
            h_s[tid] = hn;
            hkeep = hn;
            if (hs) hs[(size_t)(bl * T_LEN + tt) * 256 + dir * HD + tid] = f2bf(hn);
        }
        LDS_BARRIER();
        tt += step;
    }
    if (hTf && tid < HD) {
        (dir ? hTb : hTf)[(size_t)(bOff + bl) * HD + tid] = hkeep;
    }
}

// ---------- final FC + log_softmax ----------
__global__ __launch_bounds__(256)
void fc_lsm(const float* __restrict__ hTf, const float* __restrict__ hTb,
            const float* __restrict__ Wfc, const float* __restrict__ bfc,
            float* __restrict__ out)
{
    int b = threadIdx.x;
    const float* hb = hTb + (size_t)b * HD;
    const float* hf = hTf + (size_t)b * HD;
    float l[NC];
#pragma unroll
    for (int cc = 0; cc < NC; ++cc) {
        const float* wr = Wfc + cc * 256;
        float acc = bfc[cc];
        for (int k = 0; k < HD; k += 4) {
            acc += hb[k] * wr[k] + hb[k + 1] * wr[k + 1]
                 + hb[k + 2] * wr[k + 2] + hb[k + 3] * wr[k + 3];
            acc += hf[k] * wr[128 + k] + hf[k + 1] * wr[128 + k + 1]
                 + hf[k + 2] * wr[128 + k + 2] + hf[k + 3] * wr[128 + k + 3];
        }
        l[cc] = acc;
    }
    float m = l[0];
#pragma unroll
    for (int cc = 1; cc < NC; ++cc) m = fmaxf(m, l[cc]);
    float s = 0.0f;
#pragma unroll
    for (int cc = 0; cc < NC; ++cc) s += __expf(l[cc] - m);
    float lg = m + logf(s);
#pragma unroll
    for (int cc = 0; cc < NC; ++cc) out[(size_t)b * NC + cc] = l[cc] - lg;
}

extern "C" void kernel_launch(void* const* d_in, const int* in_sizes, int n_in,
                              void* d_out, int out_size, void* d_ws, size_t ws_size,
                              hipStream_t stream)
{
    const float* X    = (const float*)d_in[0];
    const int*   len  = (const int*)d_in[1];
    const float* Wih0 = (const float*)d_in[2];   // (2,512,64)  -> (1024,64)
    const float* Whh0 = (const float*)d_in[3];   // (2,512,128)
    const float* b0   = (const float*)d_in[4];   // (2,512) -> (1024)
    const float* Wih1 = (const float*)d_in[5];   // (2,512,256) -> (1024,256)
    const float* Whh1 = (const float*)d_in[6];
    const float* b1   = (const float*)d_in[7];
    const float* Wfc  = (const float*)d_in[8];   // (12,256)
    const float* bfc  = (const float*)d_in[9];   // (12)
    float* out = (float*)d_out;

    char* ws = (char*)d_ws;
    size_t off = 0;
    unsigned short* xg = (unsigned short*)(ws + off); off += (size_t)ROWS * 1024 * 2;
    unsigned short* h1 = (unsigned short*)(ws + off); off += (size_t)ROWS * 256 * 2;
    float* hTf = (float*)(ws + off); off += (size_t)B_ALL * HD * 4;
    float* hTb = (float*)(ws + off); off += (size_t)B_ALL * HD * 4;
    unsigned short* W0hi = (unsigned short*)(ws + off); off += 1024 * 64 * 2;
    unsigned short* W0lo = (unsigned short*)(ws + off); off += 1024 * 64 * 2;
    unsigned short* W1hi = (unsigned short*)(ws + off); off += 1024 * 256 * 2;
    unsigned short* W1lo = (unsigned short*)(ws + off); off += 1024 * 256 * 2;

    split_w<<<(1024 * 64 + 255) / 256, 256, 0, stream>>>(Wih0, W0hi, W0lo, 1024 * 64);
    split_w<<<(1024 * 256 + 255) / 256, 256, 0, stream>>>(Wih1, W1hi, W1lo, 1024 * 256);

    for (int ch = 0; ch < 2; ++ch) {
        const int* lc = len + ch * BCH;
        const float* Xc = X + (size_t)ch * BCH * T_LEN * D_INP;

        gates_gemm_mfma<3, float><<<dim3(ROWS / 128, 8), 256, 0, stream>>>(
            Xc, W0hi, W0lo, b0, lc, xg, D_INP);
        lstm_rec<<<2 * BCH, 512, 0, stream>>>(xg, Whh0, lc, h1,
                                              nullptr, nullptr, 0);
        gates_gemm_mfma<2, unsigned short><<<dim3(ROWS / 128, 8), 256, 0, stream>>>(
            h1, W1hi, W1lo, b1, lc, xg, 2 * HD);
        lstm_rec<<<2 * BCH, 512, 0, stream>>>(xg, Whh1, lc, nullptr,
                                              hTf, hTb, ch * BCH);
    }
    fc_lsm<<<1, 256, 0, stream>>>(hTf, hTb, Wfc, bfc, out);
}

// Round 16
// 1964.867 us; speedup vs baseline: 1.2248x; 1.2248x over previous
//
#include <hip/hip_runtime.h>
#include <hip/hip_bf16.h>
#include <cstdint>
#include <cstddef>
#include <type_traits>

#define B_ALL 256
#define T_LEN 512
#define D_INP 64
#define HD    128
#define G4    512            // 4*H
#define NC    12
#define BCH   128            // batch per chunk
#define ROWS  (BCH * T_LEN)  // 65536 rows per chunk

// ---------- helpers ----------
__device__ __forceinline__ float bf2f(unsigned short u) {
    union { unsigned int i; float f; } v; v.i = ((unsigned int)u) << 16; return v.f;
}
__device__ __forceinline__ unsigned short f2bf(float f) {
    union { float f; unsigned int i; } v; v.f = f;
    unsigned int r = v.i + 0x7FFFu + ((v.i >> 16) & 1u);  // round-nearest-even
    return (unsigned short)(r >> 16);
}
__device__ __forceinline__ float sigf(float x) { return 1.0f / (1.0f + __expf(-x)); }
__device__ __forceinline__ float tanh_f(float x) {
    float xx = fminf(15.0f, fmaxf(-15.0f, x));
    float e = __expf(2.0f * xx);
    return (e - 1.0f) / (e + 1.0f);
}

// LDS-only barrier: drains lgkmcnt but leaves global loads/stores in flight.
#define LDS_BARRIER() asm volatile("s_waitcnt lgkmcnt(0)\n\ts_barrier" ::: "memory")

using bf16x8 = __attribute__((ext_vector_type(8))) short;
using f32x4  = __attribute__((ext_vector_type(4))) float;

// XOR swizzle for [R][32] bf16 LDS tiles (64B rows). (r&3)<<4: the proven
// R3-R13 layout.
__device__ __forceinline__ int swz(int r, int kb) {
    return (r * 64 + kb) ^ ((r & 3) << 4);
}

// ---------- W split: fp32 -> hi/lo bf16 pair (hi+lo ~ fp32 exact) ----------
__global__ __launch_bounds__(256)
void split_w(const float* __restrict__ w, unsigned short* __restrict__ hi,
             unsigned short* __restrict__ lo, int n)
{
    int i = blockIdx.x * 256 + threadIdx.x;
    if (i < n) {
        float f = w[i];
        unsigned short h = f2bf(f);
        hi[i] = h;
        lo[i] = f2bf(f - bf2f(h));
    }
}

// ---------- length sort: perm[rank] = orig index, slen descending ----------
// R16 (=R15 intent): dispatch duration = max(L) over the chunk's blocks
// (1 block/CU, all start together; measured 509 steps x 2440 cy = 525 us).
// Sorting lengths and chunking [long 128 | short 128] cuts the short chunk's
// rec dispatches from ~509 to ~257 steps (128th order stat of 256 uniforms).
// Math per problem is bit-identical; only execution order changes.
__global__ __launch_bounds__(256)
void sort_lens(const int* __restrict__ len, int* __restrict__ perm,
               int* __restrict__ slen)
{
    __shared__ int sl[B_ALL];
    int i = threadIdx.x;
    sl[i] = len[i];
    __syncthreads();
    int li = sl[i];
    int rank = 0;
    for (int j = 0; j < B_ALL; ++j) {
        int lj = sl[j];
        rank += (lj > li) || (lj == li && j < i);   // descending, stable
    }
    perm[rank] = i;
    slen[rank] = li;
}

// ---------- gates GEMM (MFMA, split-precision bf16) ----------
// perm != nullptr: A rows are gathered from element perm[slotOff+bl]
// (layer-0 reads X in original batch space). perm == nullptr: A is already
// in local slot space (layer-1 reads h1). Output xg is always slot-space.
template <int TERMS, typename TA>
__global__ __launch_bounds__(256)
void gates_gemm_mfma(const TA* __restrict__ A,
                     const unsigned short* __restrict__ Whi_g,
                     const unsigned short* __restrict__ Wlo_g,
                     const float* __restrict__ bias,
                     const int* __restrict__ lens,
                     unsigned short* __restrict__ out, int K,
                     const int* __restrict__ perm, int slotOff)
{
    int row0 = blockIdx.x * 128;
    int col0 = blockIdx.y * 128;
    int bl = row0 >> 9;
    int t0 = row0 & (T_LEN - 1);
    if (t0 >= lens[bl]) return;

    size_t rowbase = perm ? ((size_t)perm[slotOff + bl] * T_LEN + t0)
                          : (size_t)row0;

    __shared__ __align__(16) char smem[TERMS == 3 ? 32768 : 24576];
    char* sAhi = smem;                 // [128][32] bf16, swizzled
    char* sWhi = smem + 8192;
    char* sWlo = smem + 16384;
    char* sAlo = (TERMS == 3) ? smem + 24576 : smem;

    int tid = threadIdx.x;
    int l   = tid & 63;
    int w   = tid >> 6;
    int wr  = (w >> 1) * 64;
    int wc  = (w & 1) * 64;

    f32x4 acc[4][4];
#pragma unroll
    for (int mi = 0; mi < 4; ++mi)
#pragma unroll
        for (int ni = 0; ni < 4; ++ni) acc[mi][ni] = (f32x4){0.f, 0.f, 0.f, 0.f};

    int fr = l & 15;
    int fk = (l >> 4) * 16;

    for (int kt = 0; kt < K; kt += 32) {
#pragma unroll
        for (int q = 0; q < 2; ++q) {
            int c = tid + 256 * q;
            int r = c >> 2, kc = c & 3;
            size_t gi = (size_t)(col0 + r) * K + kt + kc * 8;
            *(uint4*)(sWhi + swz(r, kc * 16)) = *(const uint4*)&Whi_g[gi];
            *(uint4*)(sWlo + swz(r, kc * 16)) = *(const uint4*)&Wlo_g[gi];
        }
        if constexpr (std::is_same<TA, unsigned short>::value) {
#pragma unroll
            for (int q = 0; q < 2; ++q) {
                int c = tid + 256 * q;
                int r = c >> 2, kc = c & 3;
                *(uint4*)(sAhi + swz(r, kc * 16)) =
                    *(const uint4*)&A[(rowbase + r) * K + kt + kc * 8];
            }
        } else {
#pragma unroll
            for (int q = 0; q < 4; ++q) {
                int c = tid + 256 * q;
                int r = c >> 3, kc = c & 7;
                float4 f = *(const float4*)&A[(rowbase + r) * K + kt + kc * 4];
                ushort4 h, lo;
                h.x = f2bf(f.x); lo.x = f2bf(f.x - bf2f(h.x));
                h.y = f2bf(f.y); lo.y = f2bf(f.y - bf2f(h.y));
                h.z = f2bf(f.z); lo.z = f2bf(f.z - bf2f(h.z));
                h.w = f2bf(f.w); lo.w = f2bf(f.w - bf2f(h.w));
                *(ushort4*)(sAhi + swz(r, kc * 8)) = h;
                *(ushort4*)(sAlo + swz(r, kc * 8)) = lo;
            }
        }
        __syncthreads();

        bf16x8 ah[4], al[4], bh[4], bl4[4];
#pragma unroll
        for (int mi = 0; mi < 4; ++mi) {
            int off = swz(wr + mi * 16 + fr, fk);
            ah[mi] = *(const bf16x8*)(sAhi + off);
            if (TERMS == 3) al[mi] = *(const bf16x8*)(sAlo + off);
        }
#pragma unroll
        for (int ni = 0; ni < 4; ++ni) {
            int off = swz(wc + ni * 16 + fr, fk);
            bh[ni]  = *(const bf16x8*)(sWhi + off);
            bl4[ni] = *(const bf16x8*)(sWlo + off);
        }
#pragma unroll
        for (int mi = 0; mi < 4; ++mi)
#pragma unroll
            for (int ni = 0; ni < 4; ++ni) {
                acc[mi][ni] = __builtin_amdgcn_mfma_f32_16x16x32_bf16(
                    ah[mi], bh[ni], acc[mi][ni], 0, 0, 0);
                acc[mi][ni] = __builtin_amdgcn_mfma_f32_16x16x32_bf16(
                    ah[mi], bl4[ni], acc[mi][ni], 0, 0, 0);
                if (TERMS == 3)
                    acc[mi][ni] = __builtin_amdgcn_mfma_f32_16x16x32_bf16(
                        al[mi], bh[ni], acc[mi][ni], 0, 0, 0);
            }
        __syncthreads();
    }

    int r4 = (l >> 4) * 4;
#pragma unroll
    for (int ni = 0; ni < 4; ++ni) {
        int col = col0 + wc + ni * 16 + fr;
        float bj = bias[col];
#pragma unroll
        for (int mi = 0; mi < 4; ++mi) {
            int row = row0 + wr + mi * 16 + r4;
            f32x4 v = acc[mi][ni];
#pragma unroll
            for (int r = 0; r < 4; ++r)
                out[(size_t)(row + r) * 1024 + col] = f2bf(v[r] + bj);
        }
    }
}

// ---------- LSTM recurrence: proven R3/R5 structure ----------
// Operates in slot space; final hT scatters to ORIGINAL batch position via
// perm (only when hTf != nullptr).
__global__ __launch_bounds__(512)
void lstm_rec(const unsigned short* __restrict__ xg,   // [ROWS][1024] slot space
              const float* __restrict__ Whh,           // [2][512][128]
              const int* __restrict__ lens,            // sorted, chunk-offset
              unsigned short* __restrict__ hs,         // [ROWS][256] or null
              float* __restrict__ hTf, float* __restrict__ hTb,
              const int* __restrict__ perm, int slotOff)
{
    int dir = blockIdx.x >> 7;   // 128 batch per chunk
    int bl  = blockIdx.x & 127;
    int L   = lens[bl];
    int tid = threadIdx.x;
    int ks  = tid >> 7;          // k-quarter 0..3 (wave-uniform)
    int rr  = tid & 127;         // output index 0..127

    __shared__ float h_s[HD];
    __shared__ float gp[4][G4];

    float w[4][32];
#pragma unroll
    for (int g = 0; g < 4; ++g) {
        const float* wrow = Whh + ((size_t)dir * G4 + g * HD + rr) * HD + ks * 32;
#pragma unroll
        for (int k = 0; k < 32; k += 4) {
            float4 v = *(const float4*)(wrow + k);
            w[g][k] = v.x; w[g][k + 1] = v.y; w[g][k + 2] = v.z; w[g][k + 3] = v.w;
        }
    }

    if (tid < HD) h_s[tid] = 0.0f;
    float c = 0.0f, hkeep = 0.0f;
    __syncthreads();

    const unsigned short* xgb = xg + (size_t)bl * T_LEN * 1024 + (size_t)dir * G4;
    int tt   = dir ? (L - 1) : 0;
    int step = dir ? -1 : 1;

    float xv0 = 0.f, xv1 = 0.f, xv2 = 0.f, xv3 = 0.f;
    if (tid < HD) {
        const unsigned short* p = xgb + (size_t)tt * 1024;
        xv0 = bf2f(p[tid]);       xv1 = bf2f(p[tid + 128]);
        xv2 = bf2f(p[tid + 256]); xv3 = bf2f(p[tid + 384]);
    }

    for (int t = 0; t < L; ++t) {
        float a0 = 0.f, a1 = 0.f, a2 = 0.f, a3 = 0.f;
        const float* hq = &h_s[ks * 32];
#pragma unroll
        for (int k = 0; k < 32; k += 4) {
            float4 h4 = *(const float4*)(hq + k);
            a0 += w[0][k] * h4.x + w[0][k+1] * h4.y + w[0][k+2] * h4.z + w[0][k+3] * h4.w;
            a1 += w[1][k] * h4.x + w[1][k+1] * h4.y + w[1][k+2] * h4.z + w[1][k+3] * h4.w;
            a2 += w[2][k] * h4.x + w[2][k+1] * h4.y + w[2][k+2] * h4.z + w[2][k+3] * h4.w;
            a3 += w[3][k] * h4.x + w[3][k+1] * h4.y + w[3][k+2] * h4.z + w[3][k+3] * h4.w;
        }
        gp[ks][rr]       = a0;
        gp[ks][rr + 128] = a1;
        gp[ks][rr + 256] = a2;
        gp[ks][rr + 384] = a3;
        LDS_BARRIER();

        if (tid < HD) {
            float gi = xv0 + ((gp[0][tid]       + gp[1][tid])       + (gp[2][tid]       + gp[3][tid]));
            float gf = xv1 + ((gp[0][tid + 128] + gp[1][tid + 128]) + (gp[2][tid + 128] + gp[3][tid + 128]));
            float gg = xv2 + ((gp[0][tid + 256] + gp[1][tid + 256]) + (gp[2][tid + 256] + gp[3][tid + 256]));
            float go = xv3 + ((gp[0][tid + 384] + gp[1][tid + 384]) + (gp[2][tid + 384] + gp[3][tid + 384]));

            int ttn = (t + 1 < L) ? (tt + step) : tt;
            const unsigned short* p = xgb + (size_t)ttn * 1024;
            xv0 = bf2f(p[tid]);       xv1 = bf2f(p[tid + 128]);
            xv2 = bf2f(p[tid + 256]); xv3 = bf2f(p[tid + 384]);

            float ig = sigf(gi);
            float fg = sigf(gf);
            float G  = tanh_f(gg);
            float og = sigf(go);
            c = fg * c + ig * G;
            float hn = og * tanh_f(c);
            h_s[tid] = hn;
            hkeep = hn;
            if (hs) hs[(size_t)(bl * T_LEN + tt) * 256 + dir * HD + tid] = f2bf(hn);
        }
        LDS_BARRIER();
        tt += step;
    }
    if (hTf && tid < HD) {
        int orig = perm[slotOff + bl];   // scatter back to original batch index
        (dir ? hTb : hTf)[(size_t)orig * HD + tid] = hkeep;
    }
}

// ---------- final FC + log_softmax ----------
__global__ __launch_bounds__(256)
void fc_lsm(const float* __restrict__ hTf, const float* __restrict__ hTb,
            const float* __restrict__ Wfc, const float* __restrict__ bfc,
            float* __restrict__ out)
{
    int b = threadIdx.x;
    const float* hb = hTb + (size_t)b * HD;
    const float* hf = hTf + (size_t)b * HD;
    float l[NC];
#pragma unroll
    for (int cc = 0; cc < NC; ++cc) {
        const float* wr = Wfc + cc * 256;
        float acc = bfc[cc];
        for (int k = 0; k < HD; k += 4) {
            acc += hb[k] * wr[k] + hb[k + 1] * wr[k + 1]
                 + hb[k + 2] * wr[k + 2] + hb[k + 3] * wr[k + 3];
            acc += hf[k] * wr[128 + k] + hf[k + 1] * wr[128 + k + 1]
                 + hf[k + 2] * wr[128 + k + 2] + hf[k + 3] * wr[128 + k + 3];
        }
        l[cc] = acc;
    }
    float m = l[0];
#pragma unroll
    for (int cc = 1; cc < NC; ++cc) m = fmaxf(m, l[cc]);
    float s = 0.0f;
#pragma unroll
    for (int cc = 0; cc < NC; ++cc) s += __expf(l[cc] - m);
    float lg = m + logf(s);
#pragma unroll
    for (int cc = 0; cc < NC; ++cc) out[(size_t)b * NC + cc] = l[cc] - lg;
}

extern "C" void kernel_launch(void* const* d_in, const int* in_sizes, int n_in,
                              void* d_out, int out_size, void* d_ws, size_t ws_size,
                              hipStream_t stream)
{
    const float* X    = (const float*)d_in[0];
    const int*   len  = (const int*)d_in[1];
    const float* Wih0 = (const float*)d_in[2];   // (2,512,64)  -> (1024,64)
    const float* Whh0 = (const float*)d_in[3];   // (2,512,128)
    const float* b0   = (const float*)d_in[4];   // (2,512) -> (1024)
    const float* Wih1 = (const float*)d_in[5];   // (2,512,256) -> (1024,256)
    const float* Whh1 = (const float*)d_in[6];
    const float* b1   = (const float*)d_in[7];
    const float* Wfc  = (const float*)d_in[8];   // (12,256)
    const float* bfc  = (const float*)d_in[9];   // (12)
    float* out = (float*)d_out;

    char* ws = (char*)d_ws;
    size_t off = 0;
    unsigned short* xg = (unsigned short*)(ws + off); off += (size_t)ROWS * 1024 * 2;
    unsigned short* h1 = (unsigned short*)(ws + off); off += (size_t)ROWS * 256 * 2;
    float* hTf = (float*)(ws + off); off += (size_t)B_ALL * HD * 4;
    float* hTb = (float*)(ws + off); off += (size_t)B_ALL * HD * 4;
    unsigned short* W0hi = (unsigned short*)(ws + off); off += 1024 * 64 * 2;
    unsigned short* W0lo = (unsigned short*)(ws + off); off += 1024 * 64 * 2;
    unsigned short* W1hi = (unsigned short*)(ws + off); off += 1024 * 256 * 2;
    unsigned short* W1lo = (unsigned short*)(ws + off); off += 1024 * 256 * 2;
    int* perm = (int*)(ws + off); off += B_ALL * 4;
    int* slen = (int*)(ws + off); off += B_ALL * 4;

    split_w<<<(1024 * 64 + 255) / 256, 256, 0, stream>>>(Wih0, W0hi, W0lo, 1024 * 64);
    split_w<<<(1024 * 256 + 255) / 256, 256, 0, stream>>>(Wih1, W1hi, W1lo, 1024 * 256);
    sort_lens<<<1, 256, 0, stream>>>(len, perm, slen);

    // Chunk 0 = 128 longest sequences (dispatch bound ~max(L)), chunk 1 =
    // 128 shortest (dispatch bound ~median(L) ~ half the steps).
    for (int ch = 0; ch < 2; ++ch) {
        const int* lc = slen + ch * BCH;

        gates_gemm_mfma<3, float><<<dim3(ROWS / 128, 8), 256, 0, stream>>>(
            X, W0hi, W0lo, b0, lc, xg, D_INP, perm, ch * BCH);
        lstm_rec<<<2 * BCH, 512, 0, stream>>>(xg, Whh0, lc, h1,
                                              nullptr, nullptr, nullptr, 0);
        gates_gemm_mfma<2, unsigned short><<<dim3(ROWS / 128, 8), 256, 0, stream>>>(
            h1, W1hi, W1lo, b1, lc, xg, 2 * HD, nullptr, 0);
        lstm_rec<<<2 * BCH, 512, 0, stream>>>(xg, Whh1, lc, nullptr,
                                              hTf, hTb, perm, ch * BCH);
    }
    fc_lsm<<<1, 256, 0, stream>>>(hTf, hTb, Wfc, bfc, out);
}

// Round 17
// 1614.052 us; speedup vs baseline: 1.4910x; 1.2174x over previous
//
#include <hip/hip_runtime.h>
#include <hip/hip_bf16.h>
#include <cstdint>
#include <cstddef>
#include <type_traits>

#define B_ALL 256
#define T_LEN 512
#define D_INP 64
#define HD    128
#define G4    512            // 4*H
#define NC    12
#define BCH   128            // batch per chunk
#define ROWS  (BCH * T_LEN)  // 65536 rows per chunk

// ---------- helpers ----------
__device__ __forceinline__ float bf2f(unsigned short u) {
    union { unsigned int i; float f; } v; v.i = ((unsigned int)u) << 16; return v.f;
}
__device__ __forceinline__ unsigned short f2bf(float f) {
    union { float f; unsigned int i; } v; v.f = f;
    unsigned int r = v.i + 0x7FFFu + ((v.i >> 16) & 1u);  // round-nearest-even
    return (unsigned short)(r >> 16);
}
__device__ __forceinline__ float sigf(float x) { return 1.0f / (1.0f + __expf(-x)); }
__device__ __forceinline__ float tanh_f(float x) {
    float xx = fminf(15.0f, fmaxf(-15.0f, x));
    float e = __expf(2.0f * xx);
    return (e - 1.0f) / (e + 1.0f);
}

// LDS-only barrier: drains lgkmcnt but leaves global loads/stores in flight.
#define LDS_BARRIER() asm volatile("s_waitcnt lgkmcnt(0)\n\ts_barrier" ::: "memory")

using bf16x8 = __attribute__((ext_vector_type(8))) short;
using f32x4  = __attribute__((ext_vector_type(4))) float;

// XOR swizzle for [R][32] bf16 LDS tiles (64B rows). Proven R3-R13 layout.
__device__ __forceinline__ int swz(int r, int kb) {
    return (r * 64 + kb) ^ ((r & 3) << 4);
}

// ---------- W split: fp32 -> hi/lo bf16 pair (hi+lo ~ fp32 exact) ----------
__global__ __launch_bounds__(256)
void split_w(const float* __restrict__ w, unsigned short* __restrict__ hi,
             unsigned short* __restrict__ lo, int n)
{
    int i = blockIdx.x * 256 + threadIdx.x;
    if (i < n) {
        float f = w[i];
        unsigned short h = f2bf(f);
        hi[i] = h;
        lo[i] = f2bf(f - bf2f(h));
    }
}

// ---------- length sort + compact-fit flag ----------
// perm[rank] = orig index, slen descending. flag = (max L of chunk 1 <= S):
// gates the compact-stride chunk-1 buffers. Thread with rank==BCH owns
// chunk 1's max.
__global__ __launch_bounds__(256)
void sort_lens(const int* __restrict__ len, int* __restrict__ perm,
               int* __restrict__ slen, int S, int* __restrict__ flag)
{
    __shared__ int sl[B_ALL];
    int i = threadIdx.x;
    sl[i] = len[i];
    __syncthreads();
    int li = sl[i];
    int rank = 0;
    for (int j = 0; j < B_ALL; ++j) {
        int lj = sl[j];
        rank += (lj > li) || (lj == li && j < i);   // descending, stable
    }
    perm[rank] = i;
    slen[rank] = li;
    if (rank == BCH) *flag = (li <= S) ? 1 : 0;
}

// ---------- gates GEMM (MFMA, split-precision bf16) ----------
// Generic row mapping: tile index = blockIdx.x -> (bl, t0) via ceilTiles.
// A rows: perm!=null -> perm[slotOff+bl]*T_LEN + t (X, original batch space);
//         else bl*aStride + t (slot space, possibly compact).
// Out rows: bl*oStride + t, store-guarded t < oStride (partial last tile).
// flagMode: 0 always run, 1 run iff *flag, 2 run iff !*flag.
template <int TERMS, typename TA>
__global__ __launch_bounds__(256)
void gates_gemm_mfma(const TA* __restrict__ A,
                     const unsigned short* __restrict__ Whi_g,
                     const unsigned short* __restrict__ Wlo_g,
                     const float* __restrict__ bias,
                     const int* __restrict__ lens,
                     unsigned short* __restrict__ out, int K,
                     const int* __restrict__ perm, int slotOff,
                     int aStride, int oStride, int ceilTiles,
                     const int* __restrict__ flag, int flagMode)
{
    if (flagMode == 1 && *flag == 0) return;
    if (flagMode == 2 && *flag != 0) return;

    int bl = blockIdx.x / ceilTiles;
    int t0 = (blockIdx.x - bl * ceilTiles) * 128;
    int col0 = blockIdx.y * 128;
    if (t0 >= lens[bl]) return;

    size_t rowbase = perm ? ((size_t)perm[slotOff + bl] * T_LEN + t0)
                          : ((size_t)bl * aStride + t0);

    __shared__ __align__(16) char smem[TERMS == 3 ? 32768 : 24576];
    char* sAhi = smem;                 // [128][32] bf16, swizzled
    char* sWhi = smem + 8192;
    char* sWlo = smem + 16384;
    char* sAlo = (TERMS == 3) ? smem + 24576 : smem;

    int tid = threadIdx.x;
    int l   = tid & 63;
    int w   = tid >> 6;
    int wr  = (w >> 1) * 64;
    int wc  = (w & 1) * 64;

    f32x4 acc[4][4];
#pragma unroll
    for (int mi = 0; mi < 4; ++mi)
#pragma unroll
        for (int ni = 0; ni < 4; ++ni) acc[mi][ni] = (f32x4){0.f, 0.f, 0.f, 0.f};

    int fr = l & 15;
    int fk = (l >> 4) * 16;

    for (int kt = 0; kt < K; kt += 32) {
#pragma unroll
        for (int q = 0; q < 2; ++q) {
            int c = tid + 256 * q;
            int r = c >> 2, kc = c & 3;
            size_t gi = (size_t)(col0 + r) * K + kt + kc * 8;
            *(uint4*)(sWhi + swz(r, kc * 16)) = *(const uint4*)&Whi_g[gi];
            *(uint4*)(sWlo + swz(r, kc * 16)) = *(const uint4*)&Wlo_g[gi];
        }
        if constexpr (std::is_same<TA, unsigned short>::value) {
#pragma unroll
            for (int q = 0; q < 2; ++q) {
                int c = tid + 256 * q;
                int r = c >> 2, kc = c & 3;
                *(uint4*)(sAhi + swz(r, kc * 16)) =
                    *(const uint4*)&A[(rowbase + r) * K + kt + kc * 8];
            }
        } else {
#pragma unroll
            for (int q = 0; q < 4; ++q) {
                int c = tid + 256 * q;
                int r = c >> 3, kc = c & 7;
                float4 f = *(const float4*)&A[(rowbase + r) * K + kt + kc * 4];
                ushort4 h, lo;
                h.x = f2bf(f.x); lo.x = f2bf(f.x - bf2f(h.x));
                h.y = f2bf(f.y); lo.y = f2bf(f.y - bf2f(h.y));
                h.z = f2bf(f.z); lo.z = f2bf(f.z - bf2f(h.z));
                h.w = f2bf(f.w); lo.w = f2bf(f.w - bf2f(h.w));
                *(ushort4*)(sAhi + swz(r, kc * 8)) = h;
                *(ushort4*)(sAlo + swz(r, kc * 8)) = lo;
            }
        }
        __syncthreads();

        bf16x8 ah[4], al[4], bh[4], bl4[4];
#pragma unroll
        for (int mi = 0; mi < 4; ++mi) {
            int off = swz(wr + mi * 16 + fr, fk);
            ah[mi] = *(const bf16x8*)(sAhi + off);
            if (TERMS == 3) al[mi] = *(const bf16x8*)(sAlo + off);
        }
#pragma unroll
        for (int ni = 0; ni < 4; ++ni) {
            int off = swz(wc + ni * 16 + fr, fk);
            bh[ni]  = *(const bf16x8*)(sWhi + off);
            bl4[ni] = *(const bf16x8*)(sWlo + off);
        }
#pragma unroll
        for (int mi = 0; mi < 4; ++mi)
#pragma unroll
            for (int ni = 0; ni < 4; ++ni) {
                acc[mi][ni] = __builtin_amdgcn_mfma_f32_16x16x32_bf16(
                    ah[mi], bh[ni], acc[mi][ni], 0, 0, 0);
                acc[mi][ni] = __builtin_amdgcn_mfma_f32_16x16x32_bf16(
                    ah[mi], bl4[ni], acc[mi][ni], 0, 0, 0);
                if (TERMS == 3)
                    acc[mi][ni] = __builtin_amdgcn_mfma_f32_16x16x32_bf16(
                        al[mi], bh[ni], acc[mi][ni], 0, 0, 0);
            }
        __syncthreads();
    }

    int r4 = (l >> 4) * 4;
#pragma unroll
    for (int ni = 0; ni < 4; ++ni) {
        int col = col0 + wc + ni * 16 + fr;
        float bj = bias[col];
#pragma unroll
        for (int mi = 0; mi < 4; ++mi) {
            int tloc = t0 + wr + mi * 16 + r4;
            f32x4 v = acc[mi][ni];
#pragma unroll
            for (int r = 0; r < 4; ++r) {
                int t = tloc + r;
                if (t < oStride)
                    out[((size_t)bl * oStride + t) * 1024 + col] = f2bf(v[r] + bj);
            }
        }
    }
}

// ---------- LSTM recurrence: proven R3 inner loop, multi-problem blocks ----------
// Each block processes up to 2 independent (dir, elem) problems SEQUENTIALLY
// (deterministic bin-packing: pair long c0 problems with short c1 problems so
// every block runs ~ L_a + L_b ~ constant ~ 514 steps instead of two
// max-L-bounded dispatches of 509 + 257). reverse pairs rank r with 127-r.
struct RecArgs {
    const unsigned short* xg; int xgStride;   // rows per element
    const float* Whh;
    const int* lens;
    unsigned short* hs; int hsStride;
    float* hTf; float* hTb;
    const int* perm; int slotOff;
    int flagMode;                              // 0 always, 1 iff flag, 2 iff !flag
    int reverse;
};

__global__ __launch_bounds__(512)
void lstm_rec(RecArgs PA, RecArgs PB, int nProb, const int* __restrict__ flag)
{
    int tid = threadIdx.x;
    int ks  = tid >> 7;          // k-quarter 0..3 (wave-uniform)
    int rr  = tid & 127;         // output index 0..127

    __shared__ float h_s[HD];
    __shared__ float gp[4][G4];

    for (int p = 0; p < nProb; ++p) {
        RecArgs a = p ? PB : PA;
        if (a.flagMode == 1 && *flag == 0) continue;
        if (a.flagMode == 2 && *flag != 0) continue;

        int dir = blockIdx.x >> 7;
        int bl  = blockIdx.x & 127;
        if (a.reverse) bl = 127 - bl;
        int L = a.lens[bl];

        float w[4][32];
#pragma unroll
        for (int g = 0; g < 4; ++g) {
            const float* wrow = a.Whh + ((size_t)dir * G4 + g * HD + rr) * HD + ks * 32;
#pragma unroll
            for (int k = 0; k < 32; k += 4) {
                float4 v = *(const float4*)(wrow + k);
                w[g][k] = v.x; w[g][k + 1] = v.y; w[g][k + 2] = v.z; w[g][k + 3] = v.w;
            }
        }

        if (tid < HD) h_s[tid] = 0.0f;
        float c = 0.0f, hkeep = 0.0f;
        __syncthreads();

        const unsigned short* xgb =
            a.xg + (size_t)bl * a.xgStride * 1024 + (size_t)dir * G4;
        int tt   = dir ? (L - 1) : 0;
        int step = dir ? -1 : 1;

        float xv0 = 0.f, xv1 = 0.f, xv2 = 0.f, xv3 = 0.f;
        if (tid < HD) {
            const unsigned short* pp = xgb + (size_t)tt * 1024;
            xv0 = bf2f(pp[tid]);       xv1 = bf2f(pp[tid + 128]);
            xv2 = bf2f(pp[tid + 256]); xv3 = bf2f(pp[tid + 384]);
        }

        for (int t = 0; t < L; ++t) {
            float a0 = 0.f, a1 = 0.f, a2 = 0.f, a3 = 0.f;
            const float* hq = &h_s[ks * 32];
#pragma unroll
            for (int k = 0; k < 32; k += 4) {
                float4 h4 = *(const float4*)(hq + k);
                a0 += w[0][k] * h4.x + w[0][k+1] * h4.y + w[0][k+2] * h4.z + w[0][k+3] * h4.w;
                a1 += w[1][k] * h4.x + w[1][k+1] * h4.y + w[1][k+2] * h4.z + w[1][k+3] * h4.w;
                a2 += w[2][k] * h4.x + w[2][k+1] * h4.y + w[2][k+2] * h4.z + w[2][k+3] * h4.w;
                a3 += w[3][k] * h4.x + w[3][k+1] * h4.y + w[3][k+2] * h4.z + w[3][k+3] * h4.w;
            }
            gp[ks][rr]       = a0;
            gp[ks][rr + 128] = a1;
            gp[ks][rr + 256] = a2;
            gp[ks][rr + 384] = a3;
            LDS_BARRIER();

            if (tid < HD) {
                float gi = xv0 + ((gp[0][tid]       + gp[1][tid])       + (gp[2][tid]       + gp[3][tid]));
                float gf = xv1 + ((gp[0][tid + 128] + gp[1][tid + 128]) + (gp[2][tid + 128] + gp[3][tid + 128]));
                float gg = xv2 + ((gp[0][tid + 256] + gp[1][tid + 256]) + (gp[2][tid + 256] + gp[3][tid + 256]));
                float go = xv3 + ((gp[0][tid + 384] + gp[1][tid + 384]) + (gp[2][tid + 384] + gp[3][tid + 384]));

                int ttn = (t + 1 < L) ? (tt + step) : tt;
                const unsigned short* pp = xgb + (size_t)ttn * 1024;
                xv0 = bf2f(pp[tid]);       xv1 = bf2f(pp[tid + 128]);
                xv2 = bf2f(pp[tid + 256]); xv3 = bf2f(pp[tid + 384]);

                float ig = sigf(gi);
                float fg = sigf(gf);
                float G  = tanh_f(gg);
                float og = sigf(go);
                c = fg * c + ig * G;
                float hn = og * tanh_f(c);
                h_s[tid] = hn;
                hkeep = hn;
                if (a.hs)
                    a.hs[((size_t)bl * a.hsStride + tt) * 256 + dir * HD + tid] = f2bf(hn);
            }
            LDS_BARRIER();
            tt += step;
        }
        if (a.hTf && tid < HD) {
            int orig = a.perm[a.slotOff + bl];
            (dir ? a.hTb : a.hTf)[(size_t)orig * HD + tid] = hkeep;
        }
        __syncthreads();
    }
}

// ---------- final FC + log_softmax ----------
__global__ __launch_bounds__(256)
void fc_lsm(const float* __restrict__ hTf, const float* __restrict__ hTb,
            const float* __restrict__ Wfc, const float* __restrict__ bfc,
            float* __restrict__ out)
{
    int b = threadIdx.x;
    const float* hb = hTb + (size_t)b * HD;
    const float* hf = hTf + (size_t)b * HD;
    float l[NC];
#pragma unroll
    for (int cc = 0; cc < NC; ++cc) {
        const float* wr = Wfc + cc * 256;
        float acc = bfc[cc];
        for (int k = 0; k < HD; k += 4) {
            acc += hb[k] * wr[k] + hb[k + 1] * wr[k + 1]
                 + hb[k + 2] * wr[k + 2] + hb[k + 3] * wr[k + 3];
            acc += hf[k] * wr[128 + k] + hf[k + 1] * wr[128 + k + 1]
                 + hf[k + 2] * wr[128 + k + 2] + hf[k + 3] * wr[128 + k + 3];
        }
        l[cc] = acc;
    }
    float m = l[0];
#pragma unroll
    for (int cc = 1; cc < NC; ++cc) m = fmaxf(m, l[cc]);
    float s = 0.0f;
#pragma unroll
    for (int cc = 0; cc < NC; ++cc) s += __expf(l[cc] - m);
    float lg = m + logf(s);
#pragma unroll
    for (int cc = 0; cc < NC; ++cc) out[(size_t)b * NC + cc] = l[cc] - lg;
}

extern "C" void kernel_launch(void* const* d_in, const int* in_sizes, int n_in,
                              void* d_out, int out_size, void* d_ws, size_t ws_size,
                              hipStream_t stream)
{
    const float* X    = (const float*)d_in[0];
    const int*   len  = (const int*)d_in[1];
    const float* Wih0 = (const float*)d_in[2];
    const float* Whh0 = (const float*)d_in[3];
    const float* b0   = (const float*)d_in[4];
    const float* Wih1 = (const float*)d_in[5];
    const float* Whh1 = (const float*)d_in[6];
    const float* b1   = (const float*)d_in[7];
    const float* Wfc  = (const float*)d_in[8];
    const float* bfc  = (const float*)d_in[9];
    float* out = (float*)d_out;

    const size_t xgA_b = (size_t)ROWS * 2048;      // 128 MB
    const size_t h1A_b = (size_t)ROWS * 512;       // 32 MB
    const size_t hT_b  = (size_t)B_ALL * HD * 4;
    const size_t sp_b  = 2 * (1024 * 64 * 2) + 2 * (1024 * 256 * 2);
    const size_t fixed = xgA_b + h1A_b + 2 * hT_b + sp_b + 4096;

    // Adaptive compact stride S for chunk-1 buffers.
    long long rem = (long long)ws_size - (long long)fixed;
    int S1 = 0, S2 = 0;
    if (rem > 0) {
        S1 = (int)(((rem / 2560) - 128) / BCH);   // xgB (2KB/row) + h1B (512B/row)
        S2 = (int)(((rem / 2048) - 128) / BCH);   // xgB only
    }
    if (S1 > 512) S1 = 512;  if (S1 < 0) S1 = 0;  S1 &= ~7;
    if (S2 > 512) S2 = 512;  if (S2 < 0) S2 = 0;  S2 &= ~7;
    int tier = (S1 >= 224) ? 1 : ((S2 >= 224) ? 2 : 3);
    int S = (tier == 1) ? S1 : S2;
    int ceilS = (S + 127) / 128;

    char* ws = (char*)d_ws;
    size_t off = 0;
    unsigned short* xgA = (unsigned short*)(ws + off); off += xgA_b;
    unsigned short* h1A = (unsigned short*)(ws + off); off += h1A_b;
    float* hTf = (float*)(ws + off); off += hT_b;
    float* hTb = (float*)(ws + off); off += hT_b;
    unsigned short* W0hi = (unsigned short*)(ws + off); off += 1024 * 64 * 2;
    unsigned short* W0lo = (unsigned short*)(ws + off); off += 1024 * 64 * 2;
    unsigned short* W1hi = (unsigned short*)(ws + off); off += 1024 * 256 * 2;
    unsigned short* W1lo = (unsigned short*)(ws + off); off += 1024 * 256 * 2;
    int* perm = (int*)(ws + off); off += B_ALL * 4;
    int* slen = (int*)(ws + off); off += B_ALL * 4;
    int* flag = (int*)(ws + off); off += 64;
    unsigned short* xgB = (unsigned short*)(ws + off);
    unsigned short* h1B = nullptr;
    if (tier == 1) {
        off += (size_t)(BCH * S + 128) * 2048;
        h1B = (unsigned short*)(ws + off);
    }

    split_w<<<(1024 * 64 + 255) / 256, 256, 0, stream>>>(Wih0, W0hi, W0lo, 1024 * 64);
    split_w<<<(1024 * 256 + 255) / 256, 256, 0, stream>>>(Wih1, W1hi, W1lo, 1024 * 256);
    sort_lens<<<1, 256, 0, stream>>>(len, perm, slen, S, flag);

    const int* lc0 = slen;
    const int* lc1 = slen + BCH;
    auto RA = [&](const unsigned short* xg, int xs, const float* Whh,
                  const int* lens, unsigned short* hs, int hss,
                  float* tf, float* tb, int so, int fm, int rev) {
        RecArgs r; r.xg = xg; r.xgStride = xs; r.Whh = Whh; r.lens = lens;
        r.hs = hs; r.hsStride = hss; r.hTf = tf; r.hTb = tb;
        r.perm = perm; r.slotOff = so; r.flagMode = fm; r.reverse = rev;
        return r;
    };
    RecArgs dummy = RA(xgA, T_LEN, Whh0, lc0, nullptr, 0, nullptr, nullptr, 0, 0, 0);

    if (tier == 1) {
        // paired both layers: every block runs ~L_r + L_{255-r} ~ const steps
        gates_gemm_mfma<3, float><<<dim3(BCH * 4, 8), 256, 0, stream>>>(
            X, W0hi, W0lo, b0, lc0, xgA, D_INP, perm, 0, T_LEN, T_LEN, 4, flag, 0);
        gates_gemm_mfma<3, float><<<dim3(BCH * ceilS, 8), 256, 0, stream>>>(
            X, W0hi, W0lo, b0, lc1, xgB, D_INP, perm, BCH, S, S, ceilS, flag, 1);
        lstm_rec<<<256, 512, 0, stream>>>(
            RA(xgA, T_LEN, Whh0, lc0, h1A, T_LEN, nullptr, nullptr, 0, 0, 0),
            RA(xgB, S,     Whh0, lc1, h1B, S,     nullptr, nullptr, BCH, 1, 1),
            2, flag);
        gates_gemm_mfma<2, unsigned short><<<dim3(BCH * 4, 8), 256, 0, stream>>>(
            h1A, W1hi, W1lo, b1, lc0, xgA, 2 * HD, nullptr, 0, T_LEN, T_LEN, 4, flag, 0);
        gates_gemm_mfma<2, unsigned short><<<dim3(BCH * ceilS, 8), 256, 0, stream>>>(
            h1B, W1hi, W1lo, b1, lc1, xgB, 2 * HD, nullptr, 0, S, S, ceilS, flag, 1);
        lstm_rec<<<256, 512, 0, stream>>>(
            RA(xgA, T_LEN, Whh1, lc0, nullptr, 0, hTf, hTb, 0, 0, 0),
            RA(xgB, S,     Whh1, lc1, nullptr, 0, hTf, hTb, BCH, 1, 1),
            2, flag);
    } else if (tier == 2) {
        gates_gemm_mfma<3, float><<<dim3(BCH * 4, 8), 256, 0, stream>>>(
            X, W0hi, W0lo, b0, lc0, xgA, D_INP, perm, 0, T_LEN, T_LEN, 4, flag, 0);
        lstm_rec<<<256, 512, 0, stream>>>(
            RA(xgA, T_LEN, Whh0, lc0, h1A, T_LEN, nullptr, nullptr, 0, 0, 0),
            dummy, 1, flag);
        gates_gemm_mfma<2, unsigned short><<<dim3(BCH * 4, 8), 256, 0, stream>>>(
            h1A, W1hi, W1lo, b1, lc0, xgA, 2 * HD, nullptr, 0, T_LEN, T_LEN, 4, flag, 0);
        gates_gemm_mfma<3, float><<<dim3(BCH * ceilS, 8), 256, 0, stream>>>(
            X, W0hi, W0lo, b0, lc1, xgB, D_INP, perm, BCH, S, S, ceilS, flag, 1);
        // paired middle: r1c0 + r0c1
        lstm_rec<<<256, 512, 0, stream>>>(
            RA(xgA, T_LEN, Whh1, lc0, nullptr, 0, hTf, hTb, 0, 0, 0),
            RA(xgB, S,     Whh0, lc1, h1A, T_LEN, nullptr, nullptr, BCH, 1, 1),
            2, flag);
        gates_gemm_mfma<2, unsigned short><<<dim3(BCH * ceilS, 8), 256, 0, stream>>>(
            h1A, W1hi, W1lo, b1, lc1, xgB, 2 * HD, nullptr, 0, T_LEN, S, ceilS, flag, 1);
        lstm_rec<<<256, 512, 0, stream>>>(
            RA(xgB, S, Whh1, lc1, nullptr, 0, hTf, hTb, BCH, 1, 0),
            dummy, 1, flag);
    } else {
        // proven R16 serial path
        for (int ch = 0; ch < 2; ++ch) {
            const int* lc = slen + ch * BCH;
            gates_gemm_mfma<3, float><<<dim3(BCH * 4, 8), 256, 0, stream>>>(
                X, W0hi, W0lo, b0, lc, xgA, D_INP, perm, ch * BCH, T_LEN, T_LEN, 4, flag, 0);
            lstm_rec<<<256, 512, 0, stream>>>(
                RA(xgA, T_LEN, Whh0, lc, h1A, T_LEN, nullptr, nullptr, 0, 0, 0),
                dummy, 1, flag);
            gates_gemm_mfma<2, unsigned short><<<dim3(BCH * 4, 8), 256, 0, stream>>>(
                h1A, W1hi, W1lo, b1, lc, xgA, 2 * HD, nullptr, 0, T_LEN, T_LEN, 4, flag, 0);
            lstm_rec<<<256, 512, 0, stream>>>(
                RA(xgA, T_LEN, Whh1, lc, nullptr, 0, hTf, hTb, ch * BCH, 0, 0),
                dummy, 1, flag);
        }
    }

    if (tier == 1 || tier == 2) {
        // fallback chunk-1 serial pipeline (runs only if compact stride failed)
        gates_gemm_mfma<3, float><<<dim3(BCH * 4, 8), 256, 0, stream>>>(
            X, W0hi, W0lo, b0, lc1, xgA, D_INP, perm, BCH, T_LEN, T_LEN, 4, flag, 2);
        lstm_rec<<<256, 512, 0, stream>>>(
            RA(xgA, T_LEN, Whh0, lc1, h1A, T_LEN, nullptr, nullptr, BCH, 2, 0),
            dummy, 1, flag);
        gates_gemm_mfma<2, unsigned short><<<dim3(BCH * 4, 8), 256, 0, stream>>>(
            h1A, W1hi, W1lo, b1, lc1, xgA, 2 * HD, nullptr, 0, T_LEN, T_LEN, 4, flag, 2);
        lstm_rec<<<256, 512, 0, stream>>>(
            RA(xgA, T_LEN, Whh1, lc1, nullptr, 0, hTf, hTb, BCH, 2, 0),
            dummy, 1, flag);
    }

    fc_lsm<<<1, 256, 0, stream>>>(hTf, hTb, Wfc, bfc, out);
}

// Round 18
// 1532.087 us; speedup vs baseline: 1.5707x; 1.0535x over previous
//
#include <hip/hip_runtime.h>
#include <hip/hip_bf16.h>
#include <cstdint>
#include <cstddef>
#include <type_traits>

#define B_ALL 256
#define T_LEN 512
#define D_INP 64
#define HD    128
#define G4    512            // 4*H
#define NC    12
#define BCH   128            // batch per chunk
#define ROWS  (BCH * T_LEN)  // 65536 rows per chunk

// ---------- helpers ----------
__device__ __forceinline__ float bf2f(unsigned short u) {
    union { unsigned int i; float f; } v; v.i = ((unsigned int)u) << 16; return v.f;
}
__device__ __forceinline__ unsigned short f2bf(float f) {
    union { float f; unsigned int i; } v; v.f = f;
    unsigned int r = v.i + 0x7FFFu + ((v.i >> 16) & 1u);  // round-nearest-even
    return (unsigned short)(r >> 16);
}
// R18: v_rcp_f32 (<=1ulp, ~1e-7 rel) replaces IEEE div (v_div_scale/fmas/
// fixup, ~60-100cy latency). Two divisions sit SERIALLY on the rec's per-step
// h-chain (sigf->c->tanh(c)->h); rcp error is 5 orders below the bf16 gate
// quantization already present.
__device__ __forceinline__ float sigf(float x) {
    return __builtin_amdgcn_rcpf(1.0f + __expf(-x));
}
__device__ __forceinline__ float tanh_f(float x) {
    float xx = fminf(15.0f, fmaxf(-15.0f, x));
    float e = __expf(2.0f * xx);
    return (e - 1.0f) * __builtin_amdgcn_rcpf(e + 1.0f);
}

// LDS-only barrier: drains lgkmcnt but leaves global loads/stores in flight.
#define LDS_BARRIER() asm volatile("s_waitcnt lgkmcnt(0)\n\ts_barrier" ::: "memory")

using bf16x8 = __attribute__((ext_vector_type(8))) short;
using f32x4  = __attribute__((ext_vector_type(4))) float;

// XOR swizzle for [R][32] bf16 LDS tiles (64B rows). Proven R3-R13 layout.
__device__ __forceinline__ int swz(int r, int kb) {
    return (r * 64 + kb) ^ ((r & 3) << 4);
}

// ---------- W split: fp32 -> hi/lo bf16 pair (hi+lo ~ fp32 exact) ----------
__global__ __launch_bounds__(256)
void split_w(const float* __restrict__ w, unsigned short* __restrict__ hi,
             unsigned short* __restrict__ lo, int n)
{
    int i = blockIdx.x * 256 + threadIdx.x;
    if (i < n) {
        float f = w[i];
        unsigned short h = f2bf(f);
        hi[i] = h;
        lo[i] = f2bf(f - bf2f(h));
    }
}

// ---------- length sort + compact-fit flag ----------
__global__ __launch_bounds__(256)
void sort_lens(const int* __restrict__ len, int* __restrict__ perm,
               int* __restrict__ slen, int S, int* __restrict__ flag)
{
    __shared__ int sl[B_ALL];
    int i = threadIdx.x;
    sl[i] = len[i];
    __syncthreads();
    int li = sl[i];
    int rank = 0;
    for (int j = 0; j < B_ALL; ++j) {
        int lj = sl[j];
        rank += (lj > li) || (lj == li && j < i);   // descending, stable
    }
    perm[rank] = i;
    slen[rank] = li;
    if (rank == BCH) *flag = (li <= S) ? 1 : 0;
}

// ---------- gates GEMM (MFMA, split-precision bf16) ----------
// flagMode: 0 always run, 1 run iff *flag, 2 run iff !*flag.
template <int TERMS, typename TA>
__global__ __launch_bounds__(256)
void gates_gemm_mfma(const TA* __restrict__ A,
                     const unsigned short* __restrict__ Whi_g,
                     const unsigned short* __restrict__ Wlo_g,
                     const float* __restrict__ bias,
                     const int* __restrict__ lens,
                     unsigned short* __restrict__ out, int K,
                     const int* __restrict__ perm, int slotOff,
                     int aStride, int oStride, int ceilTiles,
                     const int* __restrict__ flag, int flagMode)
{
    if (flagMode == 1 && *flag == 0) return;
    if (flagMode == 2 && *flag != 0) return;

    int bl = blockIdx.x / ceilTiles;
    int t0 = (blockIdx.x - bl * ceilTiles) * 128;
    int col0 = blockIdx.y * 128;
    if (t0 >= lens[bl]) return;

    size_t rowbase = perm ? ((size_t)perm[slotOff + bl] * T_LEN + t0)
                          : ((size_t)bl * aStride + t0);

    __shared__ __align__(16) char smem[TERMS == 3 ? 32768 : 24576];
    char* sAhi = smem;                 // [128][32] bf16, swizzled
    char* sWhi = smem + 8192;
    char* sWlo = smem + 16384;
    char* sAlo = (TERMS == 3) ? smem + 24576 : smem;

    int tid = threadIdx.x;
    int l   = tid & 63;
    int w   = tid >> 6;
    int wr  = (w >> 1) * 64;
    int wc  = (w & 1) * 64;

    f32x4 acc[4][4];
#pragma unroll
    for (int mi = 0; mi < 4; ++mi)
#pragma unroll
        for (int ni = 0; ni < 4; ++ni) acc[mi][ni] = (f32x4){0.f, 0.f, 0.f, 0.f};

    int fr = l & 15;
    int fk = (l >> 4) * 16;

    for (int kt = 0; kt < K; kt += 32) {
#pragma unroll
        for (int q = 0; q < 2; ++q) {
            int c = tid + 256 * q;
            int r = c >> 2, kc = c & 3;
            size_t gi = (size_t)(col0 + r) * K + kt + kc * 8;
            *(uint4*)(sWhi + swz(r, kc * 16)) = *(const uint4*)&Whi_g[gi];
            *(uint4*)(sWlo + swz(r, kc * 16)) = *(const uint4*)&Wlo_g[gi];
        }
        if constexpr (std::is_same<TA, unsigned short>::value) {
#pragma unroll
            for (int q = 0; q < 2; ++q) {
                int c = tid + 256 * q;
                int r = c >> 2, kc = c & 3;
                *(uint4*)(sAhi + swz(r, kc * 16)) =
                    *(const uint4*)&A[(rowbase + r) * K + kt + kc * 8];
            }
        } else {
#pragma unroll
            for (int q = 0; q < 4; ++q) {
                int c = tid + 256 * q;
                int r = c >> 3, kc = c & 7;
                float4 f = *(const float4*)&A[(rowbase + r) * K + kt + kc * 4];
                ushort4 h, lo;
                h.x = f2bf(f.x); lo.x = f2bf(f.x - bf2f(h.x));
                h.y = f2bf(f.y); lo.y = f2bf(f.y - bf2f(h.y));
                h.z = f2bf(f.z); lo.z = f2bf(f.z - bf2f(h.z));
                h.w = f2bf(f.w); lo.w = f2bf(f.w - bf2f(h.w));
                *(ushort4*)(sAhi + swz(r, kc * 8)) = h;
                *(ushort4*)(sAlo + swz(r, kc * 8)) = lo;
            }
        }
        __syncthreads();

        bf16x8 ah[4], al[4], bh[4], bl4[4];
#pragma unroll
        for (int mi = 0; mi < 4; ++mi) {
            int off = swz(wr + mi * 16 + fr, fk);
            ah[mi] = *(const bf16x8*)(sAhi + off);
            if (TERMS == 3) al[mi] = *(const bf16x8*)(sAlo + off);
        }
#pragma unroll
        for (int ni = 0; ni < 4; ++ni) {
            int off = swz(wc + ni * 16 + fr, fk);
            bh[ni]  = *(const bf16x8*)(sWhi + off);
            bl4[ni] = *(const bf16x8*)(sWlo + off);
        }
#pragma unroll
        for (int mi = 0; mi < 4; ++mi)
#pragma unroll
            for (int ni = 0; ni < 4; ++ni) {
                acc[mi][ni] = __builtin_amdgcn_mfma_f32_16x16x32_bf16(
                    ah[mi], bh[ni], acc[mi][ni], 0, 0, 0);
                acc[mi][ni] = __builtin_amdgcn_mfma_f32_16x16x32_bf16(
                    ah[mi], bl4[ni], acc[mi][ni], 0, 0, 0);
                if (TERMS == 3)
                    acc[mi][ni] = __builtin_amdgcn_mfma_f32_16x16x32_bf16(
                        al[mi], bh[ni], acc[mi][ni], 0, 0, 0);
            }
        __syncthreads();
    }

    int r4 = (l >> 4) * 4;
#pragma unroll
    for (int ni = 0; ni < 4; ++ni) {
        int col = col0 + wc + ni * 16 + fr;
        float bj = bias[col];
#pragma unroll
        for (int mi = 0; mi < 4; ++mi) {
            int tloc = t0 + wr + mi * 16 + r4;
            f32x4 v = acc[mi][ni];
#pragma unroll
            for (int r = 0; r < 4; ++r) {
                int t = tloc + r;
                if (t < oStride)
                    out[((size_t)bl * oStride + t) * 1024 + col] = f2bf(v[r] + bj);
            }
        }
    }
}

// ---------- LSTM recurrence: proven R3 inner loop, multi-problem blocks ----------
struct RecArgs {
    const unsigned short* xg; int xgStride;   // rows per element
    const float* Whh;
    const int* lens;
    unsigned short* hs; int hsStride;
    float* hTf; float* hTb;
    const int* perm; int slotOff;
    int flagMode;                              // 0 always, 1 iff flag, 2 iff !flag
    int reverse;
};

__global__ __launch_bounds__(512)
void lstm_rec(RecArgs PA, RecArgs PB, int nProb, const int* __restrict__ flag)
{
    int tid = threadIdx.x;
    int ks  = tid >> 7;          // k-quarter 0..3 (wave-uniform)
    int rr  = tid & 127;         // output index 0..127

    __shared__ float h_s[HD];
    __shared__ float gp[4][G4];

    for (int p = 0; p < nProb; ++p) {
        RecArgs a = p ? PB : PA;
        if (a.flagMode == 1 && *flag == 0) continue;
        if (a.flagMode == 2 && *flag != 0) continue;

        int dir = blockIdx.x >> 7;
        int bl  = blockIdx.x & 127;
        if (a.reverse) bl = 127 - bl;
        int L = a.lens[bl];

        float w[4][32];
#pragma unroll
        for (int g = 0; g < 4; ++g) {
            const float* wrow = a.Whh + ((size_t)dir * G4 + g * HD + rr) * HD + ks * 32;
#pragma unroll
            for (int k = 0; k < 32; k += 4) {
                float4 v = *(const float4*)(wrow + k);
                w[g][k] = v.x; w[g][k + 1] = v.y; w[g][k + 2] = v.z; w[g][k + 3] = v.w;
            }
        }

        if (tid < HD) h_s[tid] = 0.0f;
        float c = 0.0f, hkeep = 0.0f;
        __syncthreads();

        const unsigned short* xgb =
            a.xg + (size_t)bl * a.xgStride * 1024 + (size_t)dir * G4;
        int tt   = dir ? (L - 1) : 0;
        int step = dir ? -1 : 1;

        float xv0 = 0.f, xv1 = 0.f, xv2 = 0.f, xv3 = 0.f;
        if (tid < HD) {
            const unsigned short* pp = xgb + (size_t)tt * 1024;
            xv0 = bf2f(pp[tid]);       xv1 = bf2f(pp[tid + 128]);
            xv2 = bf2f(pp[tid + 256]); xv3 = bf2f(pp[tid + 384]);
        }

        for (int t = 0; t < L; ++t) {
            float a0 = 0.f, a1 = 0.f, a2 = 0.f, a3 = 0.f;
            const float* hq = &h_s[ks * 32];
#pragma unroll
            for (int k = 0; k < 32; k += 4) {
                float4 h4 = *(const float4*)(hq + k);
                a0 += w[0][k] * h4.x + w[0][k+1] * h4.y + w[0][k+2] * h4.z + w[0][k+3] * h4.w;
                a1 += w[1][k] * h4.x + w[1][k+1] * h4.y + w[1][k+2] * h4.z + w[1][k+3] * h4.w;
                a2 += w[2][k] * h4.x + w[2][k+1] * h4.y + w[2][k+2] * h4.z + w[2][k+3] * h4.w;
                a3 += w[3][k] * h4.x + w[3][k+1] * h4.y + w[3][k+2] * h4.z + w[3][k+3] * h4.w;
            }
            gp[ks][rr]       = a0;
            gp[ks][rr + 128] = a1;
            gp[ks][rr + 256] = a2;
            gp[ks][rr + 384] = a3;
            LDS_BARRIER();

            if (tid < HD) {
                float gi = xv0 + ((gp[0][tid]       + gp[1][tid])       + (gp[2][tid]       + gp[3][tid]));
                float gf = xv1 + ((gp[0][tid + 128] + gp[1][tid + 128]) + (gp[2][tid + 128] + gp[3][tid + 128]));
                float gg = xv2 + ((gp[0][tid + 256] + gp[1][tid + 256]) + (gp[2][tid + 256] + gp[3][tid + 256]));
                float go = xv3 + ((gp[0][tid + 384] + gp[1][tid + 384]) + (gp[2][tid + 384] + gp[3][tid + 384]));

                int ttn = (t + 1 < L) ? (tt + step) : tt;
                const unsigned short* pp = xgb + (size_t)ttn * 1024;
                xv0 = bf2f(pp[tid]);       xv1 = bf2f(pp[tid + 128]);
                xv2 = bf2f(pp[tid + 256]); xv3 = bf2f(pp[tid + 384]);

                float ig = sigf(gi);
                float fg = sigf(gf);
                float G  = tanh_f(gg);
                float og = sigf(go);
                c = fg * c + ig * G;
                float hn = og * tanh_f(c);
                h_s[tid] = hn;
                hkeep = hn;
                if (a.hs)
                    a.hs[((size_t)bl * a.hsStride + tt) * 256 + dir * HD + tid] = f2bf(hn);
            }
            LDS_BARRIER();
            tt += step;
        }
        if (a.hTf && tid < HD) {
            int orig = a.perm[a.slotOff + bl];
            (dir ? a.hTb : a.hTf)[(size_t)orig * HD + tid] = hkeep;
        }
        __syncthreads();
    }
}

// ---------- final FC + log_softmax ----------
__global__ __launch_bounds__(256)
void fc_lsm(const float* __restrict__ hTf, const float* __restrict__ hTb,
            const float* __restrict__ Wfc, const float* __restrict__ bfc,
            float* __restrict__ out)
{
    int b = threadIdx.x;
    const float* hb = hTb + (size_t)b * HD;
    const float* hf = hTf + (size_t)b * HD;
    float l[NC];
#pragma unroll
    for (int cc = 0; cc < NC; ++cc) {
        const float* wr = Wfc + cc * 256;
        float acc = bfc[cc];
        for (int k = 0; k < HD; k += 4) {
            acc += hb[k] * wr[k] + hb[k + 1] * wr[k + 1]
                 + hb[k + 2] * wr[k + 2] + hb[k + 3] * wr[k + 3];
            acc += hf[k] * wr[128 + k] + hf[k + 1] * wr[128 + k + 1]
                 + hf[k + 2] * wr[128 + k + 2] + hf[k + 3] * wr[128 + k + 3];
        }
        l[cc] = acc;
    }
    float m = l[0];
#pragma unroll
    for (int cc = 1; cc < NC; ++cc) m = fmaxf(m, l[cc]);
    float s = 0.0f;
#pragma unroll
    for (int cc = 0; cc < NC; ++cc) s += __expf(l[cc] - m);
    float lg = m + logf(s);
#pragma unroll
    for (int cc = 0; cc < NC; ++cc) out[(size_t)b * NC + cc] = l[cc] - lg;
}

extern "C" void kernel_launch(void* const* d_in, const int* in_sizes, int n_in,
                              void* d_out, int out_size, void* d_ws, size_t ws_size,
                              hipStream_t stream)
{
    const float* X    = (const float*)d_in[0];
    const int*   len  = (const int*)d_in[1];
    const float* Wih0 = (const float*)d_in[2];
    const float* Whh0 = (const float*)d_in[3];
    const float* b0   = (const float*)d_in[4];
    const float* Wih1 = (const float*)d_in[5];
    const float* Whh1 = (const float*)d_in[6];
    const float* b1   = (const float*)d_in[7];
    const float* Wfc  = (const float*)d_in[8];
    const float* bfc  = (const float*)d_in[9];
    float* out = (float*)d_out;

    const size_t xgA_b = (size_t)ROWS * 2048;      // 128 MB
    const size_t h1A_b = (size_t)ROWS * 512;       // 32 MB
    const size_t hT_b  = (size_t)B_ALL * HD * 4;
    const size_t sp_b  = 2 * (1024 * 64 * 2) + 2 * (1024 * 256 * 2);
    const size_t fixed = xgA_b + h1A_b + 2 * hT_b + sp_b + 4096;

    long long rem = (long long)ws_size - (long long)fixed;
    int S1 = 0, S2 = 0;
    if (rem > 0) {
        S1 = (int)(((rem / 2560) - 128) / BCH);
        S2 = (int)(((rem / 2048) - 128) / BCH);
    }
    if (S1 > 512) S1 = 512;  if (S1 < 0) S1 = 0;  S1 &= ~7;
    if (S2 > 512) S2 = 512;  if (S2 < 0) S2 = 0;  S2 &= ~7;
    int tier = (S1 >= 224) ? 1 : ((S2 >= 224) ? 2 : 3);
    int S = (tier == 1) ? S1 : S2;
    int ceilS = (S + 127) / 128;

    char* ws = (char*)d_ws;
    size_t off = 0;
    unsigned short* xgA = (unsigned short*)(ws + off); off += xgA_b;
    unsigned short* h1A = (unsigned short*)(ws + off); off += h1A_b;
    float* hTf = (float*)(ws + off); off += hT_b;
    float* hTb = (float*)(ws + off); off += hT_b;
    unsigned short* W0hi = (unsigned short*)(ws + off); off += 1024 * 64 * 2;
    unsigned short* W0lo = (unsigned short*)(ws + off); off += 1024 * 64 * 2;
    unsigned short* W1hi = (unsigned short*)(ws + off); off += 1024 * 256 * 2;
    unsigned short* W1lo = (unsigned short*)(ws + off); off += 1024 * 256 * 2;
    int* perm = (int*)(ws + off); off += B_ALL * 4;
    int* slen = (int*)(ws + off); off += B_ALL * 4;
    int* flag = (int*)(ws + off); off += 64;
    unsigned short* xgB = (unsigned short*)(ws + off);
    unsigned short* h1B = nullptr;
    if (tier == 1) {
        off += (size_t)(BCH * S + 128) * 2048;
        h1B = (unsigned short*)(ws + off);
    }

    split_w<<<(1024 * 64 + 255) / 256, 256, 0, stream>>>(Wih0, W0hi, W0lo, 1024 * 64);
    split_w<<<(1024 * 256 + 255) / 256, 256, 0, stream>>>(Wih1, W1hi, W1lo, 1024 * 256);
    sort_lens<<<1, 256, 0, stream>>>(len, perm, slen, S, flag);

    const int* lc0 = slen;
    const int* lc1 = slen + BCH;
    auto RA = [&](const unsigned short* xg, int xs, const float* Whh,
                  const int* lens, unsigned short* hs, int hss,
                  float* tf, float* tb, int so, int fm, int rev) {
        RecArgs r; r.xg = xg; r.xgStride = xs; r.Whh = Whh; r.lens = lens;
        r.hs = hs; r.hsStride = hss; r.hTf = tf; r.hTb = tb;
        r.perm = perm; r.slotOff = so; r.flagMode = fm; r.reverse = rev;
        return r;
    };
    RecArgs dummy = RA(xgA, T_LEN, Whh0, lc0, nullptr, 0, nullptr, nullptr, 0, 0, 0);

    if (tier == 1) {
        gates_gemm_mfma<3, float><<<dim3(BCH * 4, 8), 256, 0, stream>>>(
            X, W0hi, W0lo, b0, lc0, xgA, D_INP, perm, 0, T_LEN, T_LEN, 4, flag, 0);
        gates_gemm_mfma<3, float><<<dim3(BCH * ceilS, 8), 256, 0, stream>>>(
            X, W0hi, W0lo, b0, lc1, xgB, D_INP, perm, BCH, S, S, ceilS, flag, 1);
        lstm_rec<<<256, 512, 0, stream>>>(
            RA(xgA, T_LEN, Whh0, lc0, h1A, T_LEN, nullptr, nullptr, 0, 0, 0),
            RA(xgB, S,     Whh0, lc1, h1B, S,     nullptr, nullptr, BCH, 1, 1),
            2, flag);
        gates_gemm_mfma<2, unsigned short><<<dim3(BCH * 4, 8), 256, 0, stream>>>(
            h1A, W1hi, W1lo, b1, lc0, xgA, 2 * HD, nullptr, 0, T_LEN, T_LEN, 4, flag, 0);
        gates_gemm_mfma<2, unsigned short><<<dim3(BCH * ceilS, 8), 256, 0, stream>>>(
            h1B, W1hi, W1lo, b1, lc1, xgB, 2 * HD, nullptr, 0, S, S, ceilS, flag, 1);
        lstm_rec<<<256, 512, 0, stream>>>(
            RA(xgA, T_LEN, Whh1, lc0, nullptr, 0, hTf, hTb, 0, 0, 0),
            RA(xgB, S,     Whh1, lc1, nullptr, 0, hTf, hTb, BCH, 1, 1),
            2, flag);
    } else if (tier == 2) {
        gates_gemm_mfma<3, float><<<dim3(BCH * 4, 8), 256, 0, stream>>>(
            X, W0hi, W0lo, b0, lc0, xgA, D_INP, perm, 0, T_LEN, T_LEN, 4, flag, 0);
        lstm_rec<<<256, 512, 0, stream>>>(
            RA(xgA, T_LEN, Whh0, lc0, h1A, T_LEN, nullptr, nullptr, 0, 0, 0),
            dummy, 1, flag);
        gates_gemm_mfma<2, unsigned short><<<dim3(BCH * 4, 8), 256, 0, stream>>>(
            h1A, W1hi, W1lo, b1, lc0, xgA, 2 * HD, nullptr, 0, T_LEN, T_LEN, 4, flag, 0);
        gates_gemm_mfma<3, float><<<dim3(BCH * ceilS, 8), 256, 0, stream>>>(
            X, W0hi, W0lo, b0, lc1, xgB, D_INP, perm, BCH, S, S, ceilS, flag, 1);
        lstm_rec<<<256, 512, 0, stream>>>(
            RA(xgA, T_LEN, Whh1, lc0, nullptr, 0, hTf, hTb, 0, 0, 0),
            RA(xgB, S,     Whh0, lc1, h1A, T_LEN, nullptr, nullptr, BCH, 1, 1),
            2, flag);
        gates_gemm_mfma<2, unsigned short><<<dim3(BCH * ceilS, 8), 256, 0, stream>>>(
            h1A, W1hi, W1lo, b1, lc1, xgB, 2 * HD, nullptr, 0, T_LEN, S, ceilS, flag, 1);
        lstm_rec<<<256, 512, 0, stream>>>(
            RA(xgB, S, Whh1, lc1, nullptr, 0, hTf, hTb, BCH, 1, 0),
            dummy, 1, flag);
    } else {
        for (int ch = 0; ch < 2; ++ch) {
            const int* lc = slen + ch * BCH;
            gates_gemm_mfma<3, float><<<dim3(BCH * 4, 8), 256, 0, stream>>>(
                X, W0hi, W0lo, b0, lc, xgA, D_INP, perm, ch * BCH, T_LEN, T_LEN, 4, flag, 0);
            lstm_rec<<<256, 512, 0, stream>>>(
                RA(xgA, T_LEN, Whh0, lc, h1A, T_LEN, nullptr, nullptr, 0, 0, 0),
                dummy, 1, flag);
            gates_gemm_mfma<2, unsigned short><<<dim3(BCH * 4, 8), 256, 0, stream>>>(
                h1A, W1hi, W1lo, b1, lc, xgA, 2 * HD, nullptr, 0, T_LEN, T_LEN, 4, flag, 0);
            lstm_rec<<<256, 512, 0, stream>>>(
                RA(xgA, T_LEN, Whh1, lc, nullptr, 0, hTf, hTb, ch * BCH, 0, 0),
                dummy, 1, flag);
        }
    }

    if (tier == 1 || tier == 2) {
        gates_gemm_mfma<3, float><<<dim3(BCH * 4, 8), 256, 0, stream>>>(
            X, W0hi, W0lo, b0, lc1, xgA, D_INP, perm, BCH, T_LEN, T_LEN, 4, flag, 2);
        lstm_rec<<<256, 512, 0, stream>>>(
            RA(xgA, T_LEN, Whh0, lc1, h1A, T_LEN, nullptr, nullptr, BCH, 2, 0),
            dummy, 1, flag);
        gates_gemm_mfma<2, unsigned short><<<dim3(BCH * 4, 8), 256, 0, stream>>>(
            h1A, W1hi, W1lo, b1, lc1, xgA, 2 * HD, nullptr, 0, T_LEN, T_LEN, 4, flag, 2);
        lstm_rec<<<256, 512, 0, stream>>>(
            RA(xgA, T_LEN, Whh1, lc1, nullptr, 0, hTf, hTb, BCH, 2, 0),
            dummy, 1, flag);
    }

    fc_lsm<<<1, 256, 0, stream>>>(hTf, hTb, Wfc, bfc, out);
}

// Round 19
// 1368.748 us; speedup vs baseline: 1.7582x; 1.1193x over previous
//
#include <hip/hip_runtime.h>
#include <hip/hip_bf16.h>
#include <cstdint>
#include <cstddef>
#include <type_traits>

#define B_ALL 256
#define T_LEN 512
#define D_INP 64
#define HD    128
#define G4    512            // 4*H
#define NC    12
#define BCH   128            // batch per chunk
#define ROWS  (BCH * T_LEN)  // 65536 rows per chunk

// ---------- helpers ----------
__device__ __forceinline__ float bf2f(unsigned short u) {
    union { unsigned int i; float f; } v; v.i = ((unsigned int)u) << 16; return v.f;
}
__device__ __forceinline__ unsigned short f2bf(float f) {
    union { float f; unsigned int i; } v; v.f = f;
    unsigned int r = v.i + 0x7FFFu + ((v.i >> 16) & 1u);  // round-nearest-even
    return (unsigned short)(r >> 16);
}
// rcp (<=1ulp) replaces IEEE div on the rec's serial h-chain (R18, +38us/disp).
__device__ __forceinline__ float sigf(float x) {
    return __builtin_amdgcn_rcpf(1.0f + __expf(-x));
}
__device__ __forceinline__ float tanh_f(float x) {
    float xx = fminf(15.0f, fmaxf(-15.0f, x));
    float e = __expf(2.0f * xx);
    return (e - 1.0f) * __builtin_amdgcn_rcpf(e + 1.0f);
}

// LDS-only barrier: drains lgkmcnt but leaves global loads/stores in flight.
#define LDS_BARRIER() asm volatile("s_waitcnt lgkmcnt(0)\n\ts_barrier" ::: "memory")

using bf16x8 = __attribute__((ext_vector_type(8))) short;
using f32x4  = __attribute__((ext_vector_type(4))) float;
using f16x2  = __attribute__((ext_vector_type(2))) _Float16;

// R19: v_dot2_f32_f16 runs at 2x the fp32 FMA rate on CDNA (2 FMA/lane/instr,
// f32 accumulate) -> halves the rec dot-phase ALU time. f16 rel err 2^-11 is
// BELOW the bf16 (2^-8) quantization already applied to every xg gate term.
// __has_builtin guard -> scalar fallback compiles anywhere.
__device__ __forceinline__ float dot2f(f16x2 a, f16x2 b, float c) {
#if defined(__has_builtin) && __has_builtin(__builtin_amdgcn_fdot2)
    return __builtin_amdgcn_fdot2(a, b, c, false);
#else
    return c + (float)a[0] * (float)b[0] + (float)a[1] * (float)b[1];
#endif
}

// XOR swizzle for [R][32] bf16 LDS tiles (64B rows). Proven R3-R13 layout.
__device__ __forceinline__ int swz(int r, int kb) {
    return (r * 64 + kb) ^ ((r & 3) << 4);
}

// ---------- W split: fp32 -> hi/lo bf16 pair (hi+lo ~ fp32 exact) ----------
__global__ __launch_bounds__(256)
void split_w(const float* __restrict__ w, unsigned short* __restrict__ hi,
             unsigned short* __restrict__ lo, int n)
{
    int i = blockIdx.x * 256 + threadIdx.x;
    if (i < n) {
        float f = w[i];
        unsigned short h = f2bf(f);
        hi[i] = h;
        lo[i] = f2bf(f - bf2f(h));
    }
}

// ---------- length sort + compact-fit flag ----------
__global__ __launch_bounds__(256)
void sort_lens(const int* __restrict__ len, int* __restrict__ perm,
               int* __restrict__ slen, int S, int* __restrict__ flag)
{
    __shared__ int sl[B_ALL];
    int i = threadIdx.x;
    sl[i] = len[i];
    __syncthreads();
    int li = sl[i];
    int rank = 0;
    for (int j = 0; j < B_ALL; ++j) {
        int lj = sl[j];
        rank += (lj > li) || (lj == li && j < i);   // descending, stable
    }
    perm[rank] = i;
    slen[rank] = li;
    if (rank == BCH) *flag = (li <= S) ? 1 : 0;
}

// ---------- gates GEMM (MFMA, split-precision bf16) ----------
// flagMode: 0 always run, 1 run iff *flag, 2 run iff !*flag.
template <int TERMS, typename TA>
__global__ __launch_bounds__(256)
void gates_gemm_mfma(const TA* __restrict__ A,
                     const unsigned short* __restrict__ Whi_g,
                     const unsigned short* __restrict__ Wlo_g,
                     const float* __restrict__ bias,
                     const int* __restrict__ lens,
                     unsigned short* __restrict__ out, int K,
                     const int* __restrict__ perm, int slotOff,
                     int aStride, int oStride, int ceilTiles,
                     const int* __restrict__ flag, int flagMode)
{
    if (flagMode == 1 && *flag == 0) return;
    if (flagMode == 2 && *flag != 0) return;

    int bl = blockIdx.x / ceilTiles;
    int t0 = (blockIdx.x - bl * ceilTiles) * 128;
    int col0 = blockIdx.y * 128;
    if (t0 >= lens[bl]) return;

    size_t rowbase = perm ? ((size_t)perm[slotOff + bl] * T_LEN + t0)
                          : ((size_t)bl * aStride + t0);

    __shared__ __align__(16) char smem[TERMS == 3 ? 32768 : 24576];
    char* sAhi = smem;                 // [128][32] bf16, swizzled
    char* sWhi = smem + 8192;
    char* sWlo = smem + 16384;
    char* sAlo = (TERMS == 3) ? smem + 24576 : smem;

    int tid = threadIdx.x;
    int l   = tid & 63;
    int w   = tid >> 6;
    int wr  = (w >> 1) * 64;
    int wc  = (w & 1) * 64;

    f32x4 acc[4][4];
#pragma unroll
    for (int mi = 0; mi < 4; ++mi)
#pragma unroll
        for (int ni = 0; ni < 4; ++ni) acc[mi][ni] = (f32x4){0.f, 0.f, 0.f, 0.f};

    int fr = l & 15;
    int fk = (l >> 4) * 16;

    for (int kt = 0; kt < K; kt += 32) {
#pragma unroll
        for (int q = 0; q < 2; ++q) {
            int c = tid + 256 * q;
            int r = c >> 2, kc = c & 3;
            size_t gi = (size_t)(col0 + r) * K + kt + kc * 8;
            *(uint4*)(sWhi + swz(r, kc * 16)) = *(const uint4*)&Whi_g[gi];
            *(uint4*)(sWlo + swz(r, kc * 16)) = *(const uint4*)&Wlo_g[gi];
        }
        if constexpr (std::is_same<TA, unsigned short>::value) {
#pragma unroll
            for (int q = 0; q < 2; ++q) {
                int c = tid + 256 * q;
                int r = c >> 2, kc = c & 3;
                *(uint4*)(sAhi + swz(r, kc * 16)) =
                    *(const uint4*)&A[(rowbase + r) * K + kt + kc * 8];
            }
        } else {
#pragma unroll
            for (int q = 0; q < 4; ++q) {
                int c = tid + 256 * q;
                int r = c >> 3, kc = c & 7;
                float4 f = *(const float4*)&A[(rowbase + r) * K + kt + kc * 4];
                ushort4 h, lo;
                h.x = f2bf(f.x); lo.x = f2bf(f.x - bf2f(h.x));
                h.y = f2bf(f.y); lo.y = f2bf(f.y - bf2f(h.y));
                h.z = f2bf(f.z); lo.z = f2bf(f.z - bf2f(h.z));
                h.w = f2bf(f.w); lo.w = f2bf(f.w - bf2f(h.w));
                *(ushort4*)(sAhi + swz(r, kc * 8)) = h;
                *(ushort4*)(sAlo + swz(r, kc * 8)) = lo;
            }
        }
        __syncthreads();

        bf16x8 ah[4], al[4], bh[4], bl4[4];
#pragma unroll
        for (int mi = 0; mi < 4; ++mi) {
            int off = swz(wr + mi * 16 + fr, fk);
            ah[mi] = *(const bf16x8*)(sAhi + off);
            if (TERMS == 3) al[mi] = *(const bf16x8*)(sAlo + off);
        }
#pragma unroll
        for (int ni = 0; ni < 4; ++ni) {
            int off = swz(wc + ni * 16 + fr, fk);
            bh[ni]  = *(const bf16x8*)(sWhi + off);
            bl4[ni] = *(const bf16x8*)(sWlo + off);
        }
#pragma unroll
        for (int mi = 0; mi < 4; ++mi)
#pragma unroll
            for (int ni = 0; ni < 4; ++ni) {
                acc[mi][ni] = __builtin_amdgcn_mfma_f32_16x16x32_bf16(
                    ah[mi], bh[ni], acc[mi][ni], 0, 0, 0);
                acc[mi][ni] = __builtin_amdgcn_mfma_f32_16x16x32_bf16(
                    ah[mi], bl4[ni], acc[mi][ni], 0, 0, 0);
                if (TERMS == 3)
                    acc[mi][ni] = __builtin_amdgcn_mfma_f32_16x16x32_bf16(
                        al[mi], bh[ni], acc[mi][ni], 0, 0, 0);
            }
        __syncthreads();
    }

    int r4 = (l >> 4) * 4;
#pragma unroll
    for (int ni = 0; ni < 4; ++ni) {
        int col = col0 + wc + ni * 16 + fr;
        float bj = bias[col];
#pragma unroll
        for (int mi = 0; mi < 4; ++mi) {
            int tloc = t0 + wr + mi * 16 + r4;
            f32x4 v = acc[mi][ni];
#pragma unroll
            for (int r = 0; r < 4; ++r) {
                int t = tloc + r;
                if (t < oStride)
                    out[((size_t)bl * oStride + t) * 1024 + col] = f2bf(v[r] + bj);
            }
        }
    }
}

// ---------- LSTM recurrence: R17 pairing + R18 rcp + R19 f16 dot2 ----------
struct RecArgs {
    const unsigned short* xg; int xgStride;   // rows per element
    const float* Whh;
    const int* lens;
    unsigned short* hs; int hsStride;
    float* hTf; float* hTb;
    const int* perm; int slotOff;
    int flagMode;                              // 0 always, 1 iff flag, 2 iff !flag
    int reverse;
};

__global__ __launch_bounds__(512)
void lstm_rec(RecArgs PA, RecArgs PB, int nProb, const int* __restrict__ flag)
{
    int tid = threadIdx.x;
    int ks  = tid >> 7;          // k-quarter 0..3 (wave-uniform)
    int rr  = tid & 127;         // output index 0..127

    __shared__ __align__(16) _Float16 h_s16[HD];
    __shared__ float gp[4][G4];

    for (int p = 0; p < nProb; ++p) {
        RecArgs a = p ? PB : PA;
        if (a.flagMode == 1 && *flag == 0) continue;
        if (a.flagMode == 2 && *flag != 0) continue;

        int dir = blockIdx.x >> 7;
        int bl  = blockIdx.x & 127;
        if (a.reverse) bl = 127 - bl;
        int L = a.lens[bl];

        // w as f16 pairs: 64 VGPRs (was 128 f32); feeds v_dot2_f32_f16.
        f16x2 w2[4][16];
#pragma unroll
        for (int g = 0; g < 4; ++g) {
            const float* wrow = a.Whh + ((size_t)dir * G4 + g * HD + rr) * HD + ks * 32;
#pragma unroll
            for (int k = 0; k < 32; k += 4) {
                float4 v = *(const float4*)(wrow + k);
                f16x2 p0; p0[0] = (_Float16)v.x; p0[1] = (_Float16)v.y;
                f16x2 p1; p1[0] = (_Float16)v.z; p1[1] = (_Float16)v.w;
                w2[g][k >> 1]       = p0;
                w2[g][(k >> 1) + 1] = p1;
            }
        }

        if (tid < HD) h_s16[tid] = (_Float16)0.0f;
        float c = 0.0f, hkeep = 0.0f;
        __syncthreads();

        const unsigned short* xgb =
            a.xg + (size_t)bl * a.xgStride * 1024 + (size_t)dir * G4;
        int tt   = dir ? (L - 1) : 0;
        int step = dir ? -1 : 1;

        float xv0 = 0.f, xv1 = 0.f, xv2 = 0.f, xv3 = 0.f;
        if (tid < HD) {
            const unsigned short* pp = xgb + (size_t)tt * 1024;
            xv0 = bf2f(pp[tid]);       xv1 = bf2f(pp[tid + 128]);
            xv2 = bf2f(pp[tid + 256]); xv3 = bf2f(pp[tid + 384]);
        }

        for (int t = 0; t < L; ++t) {
            // ---- dot: f16 h slice via 4 b128 broadcast reads, dot2 chains ----
            struct __align__(16) HBuf { f16x2 h[16]; } hb;
            {
                const char* hp = (const char*)&h_s16[ks * 32];
                uint4* dst = (uint4*)hb.h;
                dst[0] = *(const uint4*)(hp);
                dst[1] = *(const uint4*)(hp + 16);
                dst[2] = *(const uint4*)(hp + 32);
                dst[3] = *(const uint4*)(hp + 48);
            }
            float a0 = 0.f, a1 = 0.f, a2 = 0.f, a3 = 0.f;
#pragma unroll
            for (int k2 = 0; k2 < 16; ++k2) {
                f16x2 hp2 = hb.h[k2];
                a0 = dot2f(w2[0][k2], hp2, a0);
                a1 = dot2f(w2[1][k2], hp2, a1);
                a2 = dot2f(w2[2][k2], hp2, a2);
                a3 = dot2f(w2[3][k2], hp2, a3);
            }
            gp[ks][rr]       = a0;
            gp[ks][rr + 128] = a1;
            gp[ks][rr + 256] = a2;
            gp[ks][rr + 384] = a3;
            LDS_BARRIER();

            if (tid < HD) {
                float gi = xv0 + ((gp[0][tid]       + gp[1][tid])       + (gp[2][tid]       + gp[3][tid]));
                float gf = xv1 + ((gp[0][tid + 128] + gp[1][tid + 128]) + (gp[2][tid + 128] + gp[3][tid + 128]));
                float gg = xv2 + ((gp[0][tid + 256] + gp[1][tid + 256]) + (gp[2][tid + 256] + gp[3][tid + 256]));
                float go = xv3 + ((gp[0][tid + 384] + gp[1][tid + 384]) + (gp[2][tid + 384] + gp[3][tid + 384]));

                int ttn = (t + 1 < L) ? (tt + step) : tt;
                const unsigned short* pp = xgb + (size_t)ttn * 1024;
                xv0 = bf2f(pp[tid]);       xv1 = bf2f(pp[tid + 128]);
                xv2 = bf2f(pp[tid + 256]); xv3 = bf2f(pp[tid + 384]);

                float ig = sigf(gi);
                float fg = sigf(gf);
                float G  = tanh_f(gg);
                float og = sigf(go);
                c = fg * c + ig * G;
                float hn = og * tanh_f(c);
                h_s16[tid] = (_Float16)hn;
                hkeep = hn;
                if (a.hs)
                    a.hs[((size_t)bl * a.hsStride + tt) * 256 + dir * HD + tid] = f2bf(hn);
            }
            LDS_BARRIER();
            tt += step;
        }
        if (a.hTf && tid < HD) {
            int orig = a.perm[a.slotOff + bl];
            (dir ? a.hTb : a.hTf)[(size_t)orig * HD + tid] = hkeep;
        }
        __syncthreads();
    }
}

// ---------- final FC + log_softmax ----------
__global__ __launch_bounds__(256)
void fc_lsm(const float* __restrict__ hTf, const float* __restrict__ hTb,
            const float* __restrict__ Wfc, const float* __restrict__ bfc,
            float* __restrict__ out)
{
    int b = threadIdx.x;
    const float* hb = hTb + (size_t)b * HD;
    const float* hf = hTf + (size_t)b * HD;
    float l[NC];
#pragma unroll
    for (int cc = 0; cc < NC; ++cc) {
        const float* wr = Wfc + cc * 256;
        float acc = bfc[cc];
        for (int k = 0; k < HD; k += 4) {
            acc += hb[k] * wr[k] + hb[k + 1] * wr[k + 1]
                 + hb[k + 2] * wr[k + 2] + hb[k + 3] * wr[k + 3];
            acc += hf[k] * wr[128 + k] + hf[k + 1] * wr[128 + k + 1]
                 + hf[k + 2] * wr[128 + k + 2] + hf[k + 3] * wr[128 + k + 3];
        }
        l[cc] = acc;
    }
    float m = l[0];
#pragma unroll
    for (int cc = 1; cc < NC; ++cc) m = fmaxf(m, l[cc]);
    float s = 0.0f;
#pragma unroll
    for (int cc = 0; cc < NC; ++cc) s += __expf(l[cc] - m);
    float lg = m + logf(s);
#pragma unroll
    for (int cc = 0; cc < NC; ++cc) out[(size_t)b * NC + cc] = l[cc] - lg;
}

extern "C" void kernel_launch(void* const* d_in, const int* in_sizes, int n_in,
                              void* d_out, int out_size, void* d_ws, size_t ws_size,
                              hipStream_t stream)
{
    const float* X    = (const float*)d_in[0];
    const int*   len  = (const int*)d_in[1];
    const float* Wih0 = (const float*)d_in[2];
    const float* Whh0 = (const float*)d_in[3];
    const float* b0   = (const float*)d_in[4];
    const float* Wih1 = (const float*)d_in[5];
    const float* Whh1 = (const float*)d_in[6];
    const float* b1   = (const float*)d_in[7];
    const float* Wfc  = (const float*)d_in[8];
    const float* bfc  = (const float*)d_in[9];
    float* out = (float*)d_out;

    const size_t xgA_b = (size_t)ROWS * 2048;      // 128 MB
    const size_t h1A_b = (size_t)ROWS * 512;       // 32 MB
    const size_t hT_b  = (size_t)B_ALL * HD * 4;
    const size_t sp_b  = 2 * (1024 * 64 * 2) + 2 * (1024 * 256 * 2);
    const size_t fixed = xgA_b + h1A_b + 2 * hT_b + sp_b + 4096;

    long long rem = (long long)ws_size - (long long)fixed;
    int S1 = 0, S2 = 0;
    if (rem > 0) {
        S1 = (int)(((rem / 2560) - 128) / BCH);
        S2 = (int)(((rem / 2048) - 128) / BCH);
    }
    if (S1 > 512) S1 = 512;  if (S1 < 0) S1 = 0;  S1 &= ~7;
    if (S2 > 512) S2 = 512;  if (S2 < 0) S2 = 0;  S2 &= ~7;
    int tier = (S1 >= 224) ? 1 : ((S2 >= 224) ? 2 : 3);
    int S = (tier == 1) ? S1 : S2;
    int ceilS = (S + 127) / 128;

    char* ws = (char*)d_ws;
    size_t off = 0;
    unsigned short* xgA = (unsigned short*)(ws + off); off += xgA_b;
    unsigned short* h1A = (unsigned short*)(ws + off); off += h1A_b;
    float* hTf = (float*)(ws + off); off += hT_b;
    float* hTb = (float*)(ws + off); off += hT_b;
    unsigned short* W0hi = (unsigned short*)(ws + off); off += 1024 * 64 * 2;
    unsigned short* W0lo = (unsigned short*)(ws + off); off += 1024 * 64 * 2;
    unsigned short* W1hi = (unsigned short*)(ws + off); off += 1024 * 256 * 2;
    unsigned short* W1lo = (unsigned short*)(ws + off); off += 1024 * 256 * 2;
    int* perm = (int*)(ws + off); off += B_ALL * 4;
    int* slen = (int*)(ws + off); off += B_ALL * 4;
    int* flag = (int*)(ws + off); off += 64;
    unsigned short* xgB = (unsigned short*)(ws + off);
    unsigned short* h1B = nullptr;
    if (tier == 1) {
        off += (size_t)(BCH * S + 128) * 2048;
        h1B = (unsigned short*)(ws + off);
    }

    split_w<<<(1024 * 64 + 255) / 256, 256, 0, stream>>>(Wih0, W0hi, W0lo, 1024 * 64);
    split_w<<<(1024 * 256 + 255) / 256, 256, 0, stream>>>(Wih1, W1hi, W1lo, 1024 * 256);
    sort_lens<<<1, 256, 0, stream>>>(len, perm, slen, S, flag);

    const int* lc0 = slen;
    const int* lc1 = slen + BCH;
    auto RA = [&](const unsigned short* xg, int xs, const float* Whh,
                  const int* lens, unsigned short* hs, int hss,
                  float* tf, float* tb, int so, int fm, int rev) {
        RecArgs r; r.xg = xg; r.xgStride = xs; r.Whh = Whh; r.lens = lens;
        r.hs = hs; r.hsStride = hss; r.hTf = tf; r.hTb = tb;
        r.perm = perm; r.slotOff = so; r.flagMode = fm; r.reverse = rev;
        return r;
    };
    RecArgs dummy = RA(xgA, T_LEN, Whh0, lc0, nullptr, 0, nullptr, nullptr, 0, 0, 0);

    if (tier == 1) {
        gates_gemm_mfma<3, float><<<dim3(BCH * 4, 8), 256, 0, stream>>>(
            X, W0hi, W0lo, b0, lc0, xgA, D_INP, perm, 0, T_LEN, T_LEN, 4, flag, 0);
        gates_gemm_mfma<3, float><<<dim3(BCH * ceilS, 8), 256, 0, stream>>>(
            X, W0hi, W0lo, b0, lc1, xgB, D_INP, perm, BCH, S, S, ceilS, flag, 1);
        lstm_rec<<<256, 512, 0, stream>>>(
            RA(xgA, T_LEN, Whh0, lc0, h1A, T_LEN, nullptr, nullptr, 0, 0, 0),
            RA(xgB, S,     Whh0, lc1, h1B, S,     nullptr, nullptr, BCH, 1, 1),
            2, flag);
        gates_gemm_mfma<2, unsigned short><<<dim3(BCH * 4, 8), 256, 0, stream>>>(
            h1A, W1hi, W1lo, b1, lc0, xgA, 2 * HD, nullptr, 0, T_LEN, T_LEN, 4, flag, 0);
        gates_gemm_mfma<2, unsigned short><<<dim3(BCH * ceilS, 8), 256, 0, stream>>>(
            h1B, W1hi, W1lo, b1, lc1, xgB, 2 * HD, nullptr, 0, S, S, ceilS, flag, 1);
        lstm_rec<<<256, 512, 0, stream>>>(
            RA(xgA, T_LEN, Whh1, lc0, nullptr, 0, hTf, hTb, 0, 0, 0),
            RA(xgB, S,     Whh1, lc1, nullptr, 0, hTf, hTb, BCH, 1, 1),
            2, flag);
    } else if (tier == 2) {
        gates_gemm_mfma<3, float><<<dim3(BCH * 4, 8), 256, 0, stream>>>(
            X, W0hi, W0lo, b0, lc0, xgA, D_INP, perm, 0, T_LEN, T_LEN, 4, flag, 0);
        lstm_rec<<<256, 512, 0, stream>>>(
            RA(xgA, T_LEN, Whh0, lc0, h1A, T_LEN, nullptr, nullptr, 0, 0, 0),
            dummy, 1, flag);
        gates_gemm_mfma<2, unsigned short><<<dim3(BCH * 4, 8), 256, 0, stream>>>(
            h1A, W1hi, W1lo, b1, lc0, xgA, 2 * HD, nullptr, 0, T_LEN, T_LEN, 4, flag, 0);
        gates_gemm_mfma<3, float><<<dim3(BCH * ceilS, 8), 256, 0, stream>>>(
            X, W0hi, W0lo, b0, lc1, xgB, D_INP, perm, BCH, S, S, ceilS, flag, 1);
        lstm_rec<<<256, 512, 0, stream>>>(
            RA(xgA, T_LEN, Whh1, lc0, nullptr, 0, hTf, hTb, 0, 0, 0),
            RA(xgB, S,     Whh0, lc1, h1A, T_LEN, nullptr, nullptr, BCH, 1, 1),
            2, flag);
        gates_gemm_mfma<2, unsigned short><<<dim3(BCH * ceilS, 8), 256, 0, stream>>>(
            h1A, W1hi, W1lo, b1, lc1, xgB, 2 * HD, nullptr, 0, T_LEN, S, ceilS, flag, 1);
        lstm_rec<<<256, 512, 0, stream>>>(
            RA(xgB, S, Whh1, lc1, nullptr, 0, hTf, hTb, BCH, 1, 0),
            dummy, 1, flag);
    } else {
        for (int ch = 0; ch < 2; ++ch) {
            const int* lc = slen + ch * BCH;
            gates_gemm_mfma<3, float><<<dim3(BCH * 4, 8), 256, 0, stream>>>(
                X, W0hi, W0lo, b0, lc, xgA, D_INP, perm, ch * BCH, T_LEN, T_LEN, 4, flag, 0);
            lstm_rec<<<256, 512, 0, stream>>>(
                RA(xgA, T_LEN, Whh0, lc, h1A, T_LEN, nullptr, nullptr, 0, 0, 0),
                dummy, 1, flag);
            gates_gemm_mfma<2, unsigned short><<<dim3(BCH * 4, 8), 256, 0, stream>>>(
                h1A, W1hi, W1lo, b1, lc, xgA, 2 * HD, nullptr, 0, T_LEN, T_LEN, 4, flag, 0);
            lstm_rec<<<256, 512, 0, stream>>>(
                RA(xgA, T_LEN, Whh1, lc, nullptr, 0, hTf, hTb, ch * BCH, 0, 0),
                dummy, 1, flag);
        }
    }

    if (tier == 1 || tier == 2) {
        gates_gemm_mfma<3, float><<<dim3(BCH * 4, 8), 256, 0, stream>>>(
            X, W0hi, W0lo, b0, lc1, xgA, D_INP, perm, BCH, T_LEN, T_LEN, 4, flag, 2);
        lstm_rec<<<256, 512, 0, stream>>>(
            RA(xgA, T_LEN, Whh0, lc1, h1A, T_LEN, nullptr, nullptr, BCH, 2, 0),
            dummy, 1, flag);
        gates_gemm_mfma<2, unsigned short><<<dim3(BCH * 4, 8), 256, 0, stream>>>(
            h1A, W1hi, W1lo, b1, lc1, xgA, 2 * HD, nullptr, 0, T_LEN, T_LEN, 4, flag, 2);
        lstm_rec<<<256, 512, 0, stream>>>(
            RA(xgA, T_LEN, Whh1, lc1, nullptr, 0, hTf, hTb, BCH, 2, 0),
            dummy, 1, flag);
    }

    fc_lsm<<<1, 256, 0, stream>>>(hTf, hTb, Wfc, bfc, out);
}